// Round 9
// baseline (857.833 us; speedup 1.0000x reference)
//
#include <hip/hip_runtime.h>
#include <cmath>

namespace {

constexpr int BB = 8192;
constexpr int TT = 512;
constexpr int FF = 2048;
constexpr float EPS_LN  = 1e-5f;
constexpr float EPS_SIG = 1e-8f;

typedef _Float16 half8 __attribute__((ext_vector_type(8)));
typedef _Float16 half4 __attribute__((ext_vector_type(4)));
typedef float f32x4 __attribute__((ext_vector_type(4)));
typedef float f32x16 __attribute__((ext_vector_type(16)));

typedef __attribute__((address_space(1))) void gvoid_t;
typedef __attribute__((address_space(3))) void lvoid_t;

__device__ __forceinline__ void async16(void* lds, const void* g) {
    __builtin_amdgcn_global_load_lds((gvoid_t*)g, (lvoid_t*)lds, 16, 0, 0);
}

__device__ __forceinline__ float silu_f(float v) {
    return v / (1.0f + expf(-v));
}
// fast silu: only for f16-rounded outputs (error ~1e-6 << f16 ulp)
__device__ __forceinline__ float silu_fast(float v) {
    return v * __builtin_amdgcn_rcpf(1.0f + __expf(-v));
}

// ===== merged weight conversion: all 6 fp32->f16 conversions in ONE dispatch =====
// regions (fp32 elems): mu[0,1M) sg[1M,2M) -> cvtcat into msw_hi/lo;
// a_w1[2M,6M) a_w2[6M,10M) m_w1[10M,12M) m_w2[12M,14M) -> plain hi-only.
// All boundaries are multiples of 1024 elems -> no chunk straddles, block-uniform.
__global__ __launch_bounds__(256) void cvtall_kernel(
    const float* __restrict__ mu_w, const float* __restrict__ sg_w,
    const float* __restrict__ a_w1, const float* __restrict__ a_w2,
    const float* __restrict__ m_w1, const float* __restrict__ m_w2,
    _Float16* __restrict__ msw_hi, _Float16* __restrict__ msw_lo,
    _Float16* __restrict__ aw1, _Float16* __restrict__ aw2,
    _Float16* __restrict__ mw1, _Float16* __restrict__ mw2) {
    int i = (blockIdx.x * 256 + threadIdx.x) * 4;     // < 14,680,064
    if (i < 2097152) {                                 // mu|sig cvtcat (hi+lo)
        const float* s; int base, ii = i;
        if (i < 1048576) { s = mu_w; base = 0; }
        else             { s = sg_w; base = 262144; ii -= 1048576; }
        int dst = ((ii >> 18) << 19) + base + (ii & 262143);
        float4 v = *(const float4*)(s + ii);
        half4 h, l;
        h[0] = (_Float16)v.x; h[1] = (_Float16)v.y;
        h[2] = (_Float16)v.z; h[3] = (_Float16)v.w;
        l[0] = (_Float16)(v.x - (float)h[0]);
        l[1] = (_Float16)(v.y - (float)h[1]);
        l[2] = (_Float16)(v.z - (float)h[2]);
        l[3] = (_Float16)(v.w - (float)h[3]);
        *(half4*)(msw_hi + dst) = h;
        *(half4*)(msw_lo + dst) = l;
        return;
    }
    const float* s; _Float16* d; int ii;
    if      (i <  6291456) { s = a_w1; d = aw1; ii = i -  2097152; }
    else if (i < 10485760) { s = a_w2; d = aw2; ii = i -  6291456; }
    else if (i < 12582912) { s = m_w1; d = mw1; ii = i - 10485760; }
    else                   { s = m_w2; d = mw2; ii = i - 12582912; }
    float4 v = *(const float4*)(s + ii);
    half4 h;
    h[0] = (_Float16)v.x; h[1] = (_Float16)v.y;
    h[2] = (_Float16)v.z; h[3] = (_Float16)v.w;
    *(half4*)(d + ii) = h;
}

// ==== fused tokenizer + first layernorm: Q = silu(x@l1), h = LN(Q)*g+b (hi+lo) ====
__global__ __launch_bounds__(512) void tokln_kernel(
    const float* __restrict__ x, const float* __restrict__ l1w,
    const float* __restrict__ l1b,
    const float* __restrict__ g, const float* __restrict__ bia,
    float* __restrict__ Q, _Float16* __restrict__ Y, _Float16* __restrict__ Ylo) {
    __shared__ float red[2][8];
    const int tid = threadIdx.x, b = blockIdx.x, t = tid;
    const float x0 = x[2 * b], x1 = x[2 * b + 1];
    float qn = silu_f(fmaf(x0, l1w[2 * t], fmaf(x1, l1w[2 * t + 1], l1b[t])));
    const size_t idx = (size_t)b * TT + t;
    Q[idx] = qn;
    const int wid = tid >> 6, lane = tid & 63;
    float s = qn;
    #pragma unroll
    for (int off = 32; off > 0; off >>= 1) s += __shfl_down(s, off);
    if (lane == 0) red[0][wid] = s;
    __syncthreads();
    float tot = 0.f;
    #pragma unroll
    for (int w = 0; w < 8; ++w) tot += red[0][w];
    float mean = tot * (1.0f / TT);
    float d = qn - mean;
    float ss = d * d;
    #pragma unroll
    for (int off = 32; off > 0; off >>= 1) ss += __shfl_down(ss, off);
    if (lane == 0) red[1][wid] = ss;
    __syncthreads();
    float vtot = 0.f;
    #pragma unroll
    for (int w = 0; w < 8; ++w) vtot += red[1][w];
    float rstd = rsqrtf(vtot * (1.0f / TT) + EPS_LN);
    float o = d * rstd * g[t] + bia[t];
    _Float16 hv = (_Float16)o;
    Y[idx] = hv;
    Ylo[idx] = (_Float16)(o - (float)hv);
}

// ------- layernorm (fp32 in, f16 out, optional f16 lo residual), wave per row -------
template <bool LO>
__global__ __launch_bounds__(256) void ln_kernel(
    const float* __restrict__ X, const float* __restrict__ g,
    const float* __restrict__ bia, _Float16* __restrict__ Y,
    _Float16* __restrict__ Ylo) {
    int lane = threadIdx.x & 63;
    int row  = blockIdx.x * 4 + (threadIdx.x >> 6);
    const float* xr = X + (size_t)row * TT;
    float v[8];
    {
        float4 a = *(const float4*)(xr + lane * 8);
        float4 c = *(const float4*)(xr + lane * 8 + 4);
        v[0]=a.x; v[1]=a.y; v[2]=a.z; v[3]=a.w;
        v[4]=c.x; v[5]=c.y; v[6]=c.z; v[7]=c.w;
    }
    float s = 0.f;
    #pragma unroll
    for (int i = 0; i < 8; ++i) s += v[i];
    #pragma unroll
    for (int off = 32; off > 0; off >>= 1) s += __shfl_down(s, off);
    float mean = __shfl(s, 0) * (1.0f / TT);
    float ss = 0.f;
    #pragma unroll
    for (int i = 0; i < 8; ++i) { float d = v[i] - mean; ss = fmaf(d, d, ss); }
    #pragma unroll
    for (int off = 32; off > 0; off >>= 1) ss += __shfl_down(ss, off);
    float var  = __shfl(ss, 0) * (1.0f / TT);
    float rstd = rsqrtf(var + EPS_LN);
    half8 hv, lv;
    #pragma unroll
    for (int i = 0; i < 8; ++i) {
        int t = lane * 8 + i;
        float o = (v[i] - mean) * rstd * g[t] + bia[t];
        hv[i] = (_Float16)o;
        if (LO) lv[i] = (_Float16)(o - (float)hv[i]);
    }
    *(half8*)(Y + (size_t)row * TT + lane * 8) = hv;
    if (LO) *(half8*)(Ylo + (size_t)row * TT + lane * 8) = lv;
}

// ========== unified deep-pipelined MFMA GEMM (T3+T4+T5): C = act(A@W^T + b) (+R) =====
// Tile BM x BN, K-step BK=32, WGM x WGN waves, mfma 32x32x16 (R9: switched from
// 16x16x32 -- same FLOPs & ds_read bytes, HALF the MFMA instructions at the
// higher-efficiency shape: 2382 vs 2075 TF ubench, ~17% less matrix-pipe time).
// Fragment layouts (32x32x16): A/B row(col)=lane&31, k=(lane>>5)*8+j;
// C/D col=lane&31, row=(reg&3)+8*(reg>>2)+4*(lane>>5) [m74/m101 HW-verified].
// LDS ring of NBUF K-tile buffers; D=NBUF-1 tiles in flight; steady-state counted
// s_waitcnt vmcnt((D-1)*LPT) -- NEVER drained in the main loop; ONE raw s_barrier
// per K-iter; setprio(1) around the MFMA clusters.
// MINW=4 + LDS<=80KB -> VGPR<=128 -> 2 blocks/CU (m114 cross-block overlap).
// R7 lesson: BK=64 (144KB, 1 block/CU) REGRESSED (m132) -- keep BK=32.
// Swizzle (CPR=4 chunks/row): stage chunk sl of row r from source chunk
// sl^((r>>1)&3); fragment read at chunk ((ks*2+kh)^((r32>>1)&3)) -- read rows are
// base+r32 with base%32==0, so the per-lane key matches the staged key exactly.
// SPLIT: acc = A@W + Alo@W + A@Wlo (near-fp32 from f16 inputs).
// ACT: 0=none, 1=silu_fast, 3=tanh for cols<nsplit else none (fused mu|sig).
template <int BM, int BN, int BK, int WGM, int WGN, int NBUF, int MINW,
          bool SPLIT, int ACT, bool RESID, typename OutT>
__global__ __launch_bounds__(WGM * WGN * 64, MINW) void gemmdp_kernel(
    const _Float16* __restrict__ A, const _Float16* __restrict__ Alo,
    const _Float16* __restrict__ W, const _Float16* __restrict__ Wlo,
    const float* __restrict__ bias, const float* __restrict__ bias2,
    const float* __restrict__ R, OutT* __restrict__ C,
    int N, int K, int nsplit) {
    constexpr int THREADS = WGM * WGN * 64;
    constexpr int CPR  = BK / 8;                   // 16B chunks per row (4)
    constexpr int NS   = SPLIT ? 2 : 1;
    constexpr int D    = NBUF - 1;
    constexpr int CH_A = NS * BM * CPR;
    constexpr int CH_T = NS * (BM + BN) * CPR;
    constexpr int LPT  = CH_T / THREADS;
    static_assert(CH_T % THREADS == 0 && CH_A % THREADS == 0, "staging split");
    constexpr int ABUF = NS * BM * BK;             // halves per buf (A region)
    constexpr int WBUF = NS * BN * BK;
    constexpr int WOFF = NBUF * ABUF;
    constexpr int WTM  = BM / WGM;
    constexpr int WTN  = BN / WGN;
    constexpr int MI   = WTM / 32;                 // 32x32 output tiles
    constexpr int NI   = WTN / 32;
    static_assert(WTM % 32 == 0 && WTN % 32 == 0, "wave tile vs mfma 32x32");

    __shared__ alignas(16) _Float16 lds[NBUF * (ABUF + WBUF)];

    const int tid = threadIdx.x;
    const int m0  = blockIdx.x * BM;
    const int n0  = blockIdx.y * BN;

    const _Float16* Asrc[2] = {A, Alo};
    const _Float16* Wsrc[2] = {W, Wlo};

    // ---- staging plan (fully unrolled -> registers; per-j branch is uniform) ----
    const _Float16* gsrc[LPT];
    int off0[LPT], bstr[LPT];
    #pragma unroll
    for (int j = 0; j < LPT; ++j) {
        int idx = j * THREADS + tid;
        if (j * THREADS < CH_A) {                  // A chunk (compile-time per j)
            int s   = idx / (BM * CPR);
            int rc  = idx % (BM * CPR);
            int row = rc / CPR, sl = rc % CPR;
            int src = sl ^ ((row >> 1) & (CPR - 1));
            gsrc[j] = Asrc[s] + (size_t)(m0 + row) * K + src * 8;
            off0[j] = (s * BM + row) * BK + sl * 8;
            bstr[j] = ABUF;
        } else {                                   // W chunk
            int i2  = idx - CH_A;
            int s   = i2 / (BN * CPR);
            int rc  = i2 % (BN * CPR);
            int row = rc / CPR, sl = rc % CPR;
            int src = sl ^ ((row >> 1) & (CPR - 1));
            gsrc[j] = Wsrc[s] + (size_t)(n0 + row) * K + src * 8;
            off0[j] = WOFF + (s * BN + row) * BK + sl * 8;
            bstr[j] = WBUF;
        }
    }

    auto stage = [&](int buf, int k0) {
        #pragma unroll
        for (int j = 0; j < LPT; ++j)
            async16(&lds[off0[j] + buf * bstr[j]], gsrc[j] + k0);
    };

    // ---- fragment geometry (mfma 32x32x16) ----
    const int wid  = tid >> 6;
    const int wr   = wid / WGN;
    const int wc   = wid % WGN;
    const int lane = tid & 63;
    const int r32  = lane & 31;                    // row/col within 32-tile
    const int kh   = lane >> 5;                    // k-half (8 elems each)
    const int hxor = (r32 >> 1) & (CPR - 1);       // per-lane swizzle key

    f32x16 acc[MI][NI];
    #pragma unroll
    for (int mi = 0; mi < MI; ++mi)
        #pragma unroll
        for (int ni = 0; ni < NI; ++ni)
            #pragma unroll
            for (int r = 0; r < 16; ++r) acc[mi][ni][r] = 0.f;

    auto body = [&](int buf) {
        const int da = buf * ABUF;
        const int dw = WOFF + buf * WBUF;
        #pragma unroll
        for (int ks = 0; ks < BK / 16; ++ks) {     // 2 k-steps of K=16
            const int swz = ((ks * 2 + kh) ^ hxor) * 8;   // halves offset in row
            half8 a[NS][MI], b[NS][NI];
            #pragma unroll
            for (int s = 0; s < NS; ++s) {
                #pragma unroll
                for (int mi = 0; mi < MI; ++mi)
                    a[s][mi] = *(const half8*)&lds[da + (s * BM + wr * WTM + mi * 32 + r32) * BK + swz];
                #pragma unroll
                for (int ni = 0; ni < NI; ++ni)
                    b[s][ni] = *(const half8*)&lds[dw + (s * BN + wc * WTN + ni * 32 + r32) * BK + swz];
            }
            __builtin_amdgcn_s_setprio(1);
            #pragma unroll
            for (int mi = 0; mi < MI; ++mi)
                #pragma unroll
                for (int ni = 0; ni < NI; ++ni)
                    acc[mi][ni] = __builtin_amdgcn_mfma_f32_32x32x16_f16(
                        a[0][mi], b[0][ni], acc[mi][ni], 0, 0, 0);
            if (SPLIT) {
                #pragma unroll
                for (int mi = 0; mi < MI; ++mi)
                    #pragma unroll
                    for (int ni = 0; ni < NI; ++ni)
                        acc[mi][ni] = __builtin_amdgcn_mfma_f32_32x32x16_f16(
                            a[1][mi], b[0][ni], acc[mi][ni], 0, 0, 0);
                #pragma unroll
                for (int mi = 0; mi < MI; ++mi)
                    #pragma unroll
                    for (int ni = 0; ni < NI; ++ni)
                        acc[mi][ni] = __builtin_amdgcn_mfma_f32_32x32x16_f16(
                            a[0][mi], b[1][ni], acc[mi][ni], 0, 0, 0);
            }
            __builtin_amdgcn_s_setprio(0);
        }
    };

    const int NK = K / BK;

    #pragma unroll
    for (int s = 0; s < D; ++s) stage(s, s * BK);

    int rbuf = 0, sbuf = D;
    for (int ki = 0; ki < NK - D; ++ki) {
        asm volatile("s_waitcnt vmcnt(%0)" :: "n"((D - 1) * LPT) : "memory");
        __builtin_amdgcn_s_barrier();
        asm volatile("" ::: "memory");
        stage(sbuf, (ki + D) * BK);
        sbuf = (sbuf + 1 == NBUF) ? 0 : sbuf + 1;
        body(rbuf);
        rbuf = (rbuf + 1 == NBUF) ? 0 : rbuf + 1;
    }
    if constexpr (D >= 4) {
        asm volatile("s_waitcnt vmcnt(%0)" :: "n"(3 * LPT) : "memory");
        __builtin_amdgcn_s_barrier();
        asm volatile("" ::: "memory");
        body(rbuf);
        rbuf = (rbuf + 1 == NBUF) ? 0 : rbuf + 1;
    }
    if constexpr (D >= 3) {
        asm volatile("s_waitcnt vmcnt(%0)" :: "n"(2 * LPT) : "memory");
        __builtin_amdgcn_s_barrier();
        asm volatile("" ::: "memory");
        body(rbuf);
        rbuf = (rbuf + 1 == NBUF) ? 0 : rbuf + 1;
    }
    if constexpr (D >= 2) {
        asm volatile("s_waitcnt vmcnt(%0)" :: "n"(1 * LPT) : "memory");
        __builtin_amdgcn_s_barrier();
        asm volatile("" ::: "memory");
        body(rbuf);
        rbuf = (rbuf + 1 == NBUF) ? 0 : rbuf + 1;
    }
    asm volatile("s_waitcnt vmcnt(0)" ::: "memory");
    __builtin_amdgcn_s_barrier();
    asm volatile("" ::: "memory");
    body(rbuf);

    // ---- epilogue; C/D: col=lane&31, row=(reg&3)+8*(reg>>2)+4*kh ----
    const bool fh = (n0 < nsplit);                  // block-uniform half select
    const float* bp = fh ? bias : bias2;
    const int coff = fh ? 0 : nsplit;
    #pragma unroll
    for (int mi = 0; mi < MI; ++mi) {
        #pragma unroll
        for (int ni = 0; ni < NI; ++ni) {
            const int col = n0 + wc * WTN + ni * 32 + r32;
            const float bv = bp[col - coff];
            #pragma unroll
            for (int reg = 0; reg < 16; ++reg) {
                const int row = m0 + wr * WTM + mi * 32
                              + (reg & 3) + 8 * (reg >> 2) + 4 * kh;
                float v = acc[mi][ni][reg] + bv;
                if (ACT == 1) v = silu_fast(v);
                if (ACT == 3 && fh) v = tanhf(v);
                if (RESID) v += R[(size_t)row * N + col];
                C[(size_t)row * N + col] = (OutT)v;
            }
        }
    }
}

// ==== fused attention update + layernorm: Q += sum_k S*H; h = LN(Q)*g+b -> f16 ====
__global__ __launch_bounds__(512) void attnln_kernel(
    float* __restrict__ Q, const float* __restrict__ MS,
    const float* __restrict__ x,
    const float* __restrict__ omega, const float* __restrict__ G,
    const float* __restrict__ phase,
    const float* __restrict__ g, const float* __restrict__ bia,
    _Float16* __restrict__ Y) {
    __shared__ float cs[8][516];
    __shared__ float gs[8][516];
    __shared__ float red[2][8];
    const int tid = threadIdx.x;
    const int b   = blockIdx.x;
    const float x0 = x[2 * b], x1 = x[2 * b + 1];
    #pragma unroll
    for (int it = 0; it < 8; ++it) {
        int j = it * 512 + tid;            // 0..4095 flat (t,k) index
        float2 om = *(const float2*)(omega + 2 * j);
        float arg = fmaf(om.x, x0, fmaf(om.y, x1, phase[j]));
        cs[j & 7][j >> 3] = __cosf(arg);
        gs[j & 7][j >> 3] = G[j];
    }
    __syncthreads();
    const int t = tid;
    float mu  = MS[(size_t)b * 1024 + t];
    float sig = MS[(size_t)b * 1024 + 512 + t];
    float inv = -0.5f * __builtin_amdgcn_rcpf(fmaf(sig, sig, EPS_SIG));
    float acc = 0.f;
    #pragma unroll
    for (int k = 0; k < 8; ++k) {
        float d = gs[k][t] - mu;
        acc = fmaf(__expf(d * d * inv), cs[k][t], acc);
    }
    const size_t idx = (size_t)b * TT + t;
    float qn = Q[idx] + acc;
    Q[idx] = qn;
    const int wid = tid >> 6, lane = tid & 63;
    float s = qn;
    #pragma unroll
    for (int off = 32; off > 0; off >>= 1) s += __shfl_down(s, off);
    if (lane == 0) red[0][wid] = s;
    __syncthreads();
    float tot = 0.f;
    #pragma unroll
    for (int w = 0; w < 8; ++w) tot += red[0][w];
    float mean = tot * (1.0f / TT);
    float d = qn - mean;
    float ss = d * d;
    #pragma unroll
    for (int off = 32; off > 0; off >>= 1) ss += __shfl_down(ss, off);
    if (lane == 0) red[1][wid] = ss;
    __syncthreads();
    float vtot = 0.f;
    #pragma unroll
    for (int w = 0; w < 8; ++w) vtot += red[1][w];
    float rstd = rsqrtf(vtot * (1.0f / TT) + EPS_LN);
    Y[idx] = (_Float16)(d * rstd * g[t] + bia[t]);
}

// ---------------- readout: out[b] = silu(Q[b,:]) . ro_w + ro_b ----------------
__global__ __launch_bounds__(256) void readout_kernel(
    const float* __restrict__ Q, const float* __restrict__ row_,
    const float* __restrict__ rob, float* __restrict__ out) {
    int lane = threadIdx.x & 63;
    int row  = blockIdx.x * 4 + (threadIdx.x >> 6);
    const float* qr = Q + (size_t)row * TT;
    float acc = 0.f;
    #pragma unroll
    for (int i = 0; i < 8; ++i) {
        int t = lane * 8 + i;
        acc = fmaf(silu_f(qr[t]), row_[t], acc);
    }
    #pragma unroll
    for (int off = 32; off > 0; off >>= 1) acc += __shfl_down(acc, off);
    if (lane == 0) out[row] = acc + rob[0];
}

} // namespace

extern "C" void kernel_launch(void* const* d_in, const int* in_sizes, int n_in,
                              void* d_out, int out_size, void* d_ws, size_t ws_size,
                              hipStream_t stream) {
    const float* x     = (const float*)d_in[0];
    const float* omega = (const float*)d_in[1];
    const float* G     = (const float*)d_in[2];
    const float* phase = (const float*)d_in[3];
    const float* l1_w  = (const float*)d_in[4];
    const float* l1_b  = (const float*)d_in[5];
    const float* mu_w  = (const float*)d_in[6];
    const float* mu_b  = (const float*)d_in[7];
    const float* sg_w  = (const float*)d_in[8];
    const float* sg_b  = (const float*)d_in[9];
    const float* alqg  = (const float*)d_in[10];
    const float* alqb  = (const float*)d_in[11];
    const float* alfg  = (const float*)d_in[12];
    const float* alfb  = (const float*)d_in[13];
    const float* a_w1  = (const float*)d_in[14];
    const float* a_b1  = (const float*)d_in[15];
    const float* a_w2  = (const float*)d_in[16];
    const float* a_b2  = (const float*)d_in[17];
    const float* mln_g = (const float*)d_in[18];
    const float* mln_b = (const float*)d_in[19];
    const float* m_w1  = (const float*)d_in[20];
    const float* m_b1  = (const float*)d_in[21];
    const float* m_w2  = (const float*)d_in[22];
    const float* m_b2  = (const float*)d_in[23];
    const float* ro_w  = (const float*)d_in[24];
    const float* ro_b  = (const float*)d_in[25];

    // ---- workspace layout (total 100,663,296 B == round-1 proven footprint) ----
    char* ws = (char*)d_ws;
    float*     Q    = (float*)ws;                          // 16 MB  [B,T] fp32
    _Float16*  h_hi = (_Float16*)(ws + 16777216);          //  8 MB  [B,T] f16
    _Float16*  h_lo = (_Float16*)(ws + 25165824);          //  8 MB  [B,T] f16
    _Float16*  mid  = (_Float16*)(ws + 33554432);          // 32 MB  [B,F] f16
    float*     MS   = (float*)(ws + 33554432);             // alias on mid: [B,1024] fp32
    _Float16*  wbuf = (_Float16*)(ws + 67108864);          // 32 MB  f16 weights

    _Float16* msw_hi = wbuf;                     // 4*1024*512 (mu/sig concat)
    _Float16* msw_lo = msw_hi + 2097152;
    _Float16* aw1    = msw_lo + 2097152;         // 4*2048*512
    _Float16* aw2    = aw1 + 4194304;
    _Float16* mw1    = aw2 + 4194304;            // 2*2048*512
    _Float16* mw2    = mw1 + 2097152;

    dim3 blk(256);
    const int BIG = 1 << 30;

    // merged weight conversion (re-done every call; inputs re-poisoned by harness)
    cvtall_kernel<<<14336, blk, 0, stream>>>(
        mu_w, sg_w, a_w1, a_w2, m_w1, m_w2,
        msw_hi, msw_lo, aw1, aw2, mw1, mw2);

    // fused tokenizer + layer-0 LN (hi+lo)
    tokln_kernel<<<BB, dim3(512), 0, stream>>>(
        x, l1_w, l1_b, alqg, alqb, Q, h_hi, h_lo);

    for (int i = 0; i < 4; ++i) {
        if (i > 0)
            ln_kernel<true><<<BB / 4, blk, 0, stream>>>(
                Q, alqg + i * TT, alqb + i * TT, h_hi, h_lo);
        // fused mu|sig SPLIT GEMM: N=1024, deep pipeline, tanh on mu half only
        gemmdp_kernel<256, 128, 32, 4, 2, 3, 2, true, 3, false, float>
            <<<dim3(BB / 256, 1024 / 128), dim3(512), 0, stream>>>(
            h_hi, h_lo, msw_hi + (size_t)i * 524288, msw_lo + (size_t)i * 524288,
            mu_b + i * TT, sg_b + i * TT, nullptr, MS, 1024, TT, TT);
        // fused attention update + LN -> h_hi
        attnln_kernel<<<BB, dim3(512), 0, stream>>>(
            Q, MS, x, omega, G, phase, alfg + i * TT, alfb + i * TT, h_hi);
        // w1: BK=32, 72KB LDS, MINW=4 -> 2 blocks/CU
        gemmdp_kernel<256, 128, 32, 4, 2, 3, 4, false, 1, false, _Float16>
            <<<dim3(BB / 256, FF / 128), dim3(512), 0, stream>>>(
            h_hi, nullptr, aw1 + (size_t)i * 1048576, nullptr,
            a_b1 + i * FF, a_b1 + i * FF, nullptr, mid, FF, TT, BIG);
        // w2: NBUF=5 (80KB x 2 blocks/CU), D=4 lead
        gemmdp_kernel<128, 128, 32, 2, 4, 5, 4, false, 0, true, float>
            <<<dim3(BB / 128, TT / 128), dim3(512), 0, stream>>>(
            mid, nullptr, aw2 + (size_t)i * 1048576, nullptr,
            a_b2 + i * TT, a_b2 + i * TT, Q, Q, TT, FF, BIG);
    }
    for (int i = 0; i < 2; ++i) {
        ln_kernel<false><<<BB / 4, blk, 0, stream>>>(
            Q, mln_g + i * TT, mln_b + i * TT, h_hi, nullptr);
        gemmdp_kernel<256, 128, 32, 4, 2, 3, 4, false, 1, false, _Float16>
            <<<dim3(BB / 256, FF / 128), dim3(512), 0, stream>>>(
            h_hi, nullptr, mw1 + (size_t)i * 1048576, nullptr,
            m_b1 + i * FF, m_b1 + i * FF, nullptr, mid, FF, TT, BIG);
        gemmdp_kernel<128, 128, 32, 2, 4, 5, 4, false, 0, true, float>
            <<<dim3(BB / 128, TT / 128), dim3(512), 0, stream>>>(
            mid, nullptr, mw2 + (size_t)i * 1048576, nullptr,
            m_b2 + i * TT, m_b2 + i * TT, Q, Q, TT, FF, BIG);
    }

    readout_kernel<<<BB / 4, blk, 0, stream>>>(Q, ro_w, ro_b, (float*)d_out);
}

// Round 10
// 737.930 us; speedup vs baseline: 1.1625x; 1.1625x over previous
//
#include <hip/hip_runtime.h>
#include <cmath>

namespace {

constexpr int BB = 8192;
constexpr int TT = 512;
constexpr int FF = 2048;
constexpr float EPS_LN  = 1e-5f;
constexpr float EPS_SIG = 1e-8f;

typedef _Float16 half8 __attribute__((ext_vector_type(8)));
typedef _Float16 half4 __attribute__((ext_vector_type(4)));
typedef float f32x4 __attribute__((ext_vector_type(4)));

typedef __attribute__((address_space(1))) void gvoid_t;
typedef __attribute__((address_space(3))) void lvoid_t;

__device__ __forceinline__ void async16(void* lds, const void* g) {
    __builtin_amdgcn_global_load_lds((gvoid_t*)g, (lvoid_t*)lds, 16, 0, 0);
}

__device__ __forceinline__ float silu_f(float v) {
    return v / (1.0f + expf(-v));
}
// fast silu: only for f16-rounded outputs (error ~1e-6 << f16 ulp)
__device__ __forceinline__ float silu_fast(float v) {
    return v * __builtin_amdgcn_rcpf(1.0f + __expf(-v));
}
// fast tanh: (e^{2v}-1)/(e^{2v}+1); clamp +-10 (tanh saturates to f32 1.0 at ~9.01,
// so the clamp is exact). Error ~1e-6 on fp32 intermediate (mu), fine for the
// Gaussian S that consumes it (R2 silu_fast precedent: absmax unmoved).
__device__ __forceinline__ float tanh_fast(float v) {
    float t = __expf(2.0f * fminf(fmaxf(v, -10.0f), 10.0f));
    return (t - 1.0f) * __builtin_amdgcn_rcpf(t + 1.0f);
}

// ===== merged weight conversion: all 6 fp32->f16 conversions in ONE dispatch =====
// regions (fp32 elems): mu[0,1M) sg[1M,2M) -> cvtcat into msw_hi/lo;
// a_w1[2M,6M) a_w2[6M,10M) m_w1[10M,12M) m_w2[12M,14M) -> plain hi-only.
// All boundaries are multiples of 1024 elems -> no chunk straddles, block-uniform.
__global__ __launch_bounds__(256) void cvtall_kernel(
    const float* __restrict__ mu_w, const float* __restrict__ sg_w,
    const float* __restrict__ a_w1, const float* __restrict__ a_w2,
    const float* __restrict__ m_w1, const float* __restrict__ m_w2,
    _Float16* __restrict__ msw_hi, _Float16* __restrict__ msw_lo,
    _Float16* __restrict__ aw1, _Float16* __restrict__ aw2,
    _Float16* __restrict__ mw1, _Float16* __restrict__ mw2) {
    int i = (blockIdx.x * 256 + threadIdx.x) * 4;     // < 14,680,064
    if (i < 2097152) {                                 // mu|sig cvtcat (hi+lo)
        const float* s; int base, ii = i;
        if (i < 1048576) { s = mu_w; base = 0; }
        else             { s = sg_w; base = 262144; ii -= 1048576; }
        int dst = ((ii >> 18) << 19) + base + (ii & 262143);
        float4 v = *(const float4*)(s + ii);
        half4 h, l;
        h[0] = (_Float16)v.x; h[1] = (_Float16)v.y;
        h[2] = (_Float16)v.z; h[3] = (_Float16)v.w;
        l[0] = (_Float16)(v.x - (float)h[0]);
        l[1] = (_Float16)(v.y - (float)h[1]);
        l[2] = (_Float16)(v.z - (float)h[2]);
        l[3] = (_Float16)(v.w - (float)h[3]);
        *(half4*)(msw_hi + dst) = h;
        *(half4*)(msw_lo + dst) = l;
        return;
    }
    const float* s; _Float16* d; int ii;
    if      (i <  6291456) { s = a_w1; d = aw1; ii = i -  2097152; }
    else if (i < 10485760) { s = a_w2; d = aw2; ii = i -  6291456; }
    else if (i < 12582912) { s = m_w1; d = mw1; ii = i - 10485760; }
    else                   { s = m_w2; d = mw2; ii = i - 12582912; }
    float4 v = *(const float4*)(s + ii);
    half4 h;
    h[0] = (_Float16)v.x; h[1] = (_Float16)v.y;
    h[2] = (_Float16)v.z; h[3] = (_Float16)v.w;
    *(half4*)(d + ii) = h;
}

// ==== fused tokenizer + first layernorm: Q = silu(x@l1), h = LN(Q)*g+b (hi+lo) ====
__global__ __launch_bounds__(512) void tokln_kernel(
    const float* __restrict__ x, const float* __restrict__ l1w,
    const float* __restrict__ l1b,
    const float* __restrict__ g, const float* __restrict__ bia,
    float* __restrict__ Q, _Float16* __restrict__ Y, _Float16* __restrict__ Ylo) {
    __shared__ float red[2][8];
    const int tid = threadIdx.x, b = blockIdx.x, t = tid;
    const float x0 = x[2 * b], x1 = x[2 * b + 1];
    float qn = silu_f(fmaf(x0, l1w[2 * t], fmaf(x1, l1w[2 * t + 1], l1b[t])));
    const size_t idx = (size_t)b * TT + t;
    Q[idx] = qn;
    const int wid = tid >> 6, lane = tid & 63;
    float s = qn;
    #pragma unroll
    for (int off = 32; off > 0; off >>= 1) s += __shfl_down(s, off);
    if (lane == 0) red[0][wid] = s;
    __syncthreads();
    float tot = 0.f;
    #pragma unroll
    for (int w = 0; w < 8; ++w) tot += red[0][w];
    float mean = tot * (1.0f / TT);
    float d = qn - mean;
    float ss = d * d;
    #pragma unroll
    for (int off = 32; off > 0; off >>= 1) ss += __shfl_down(ss, off);
    if (lane == 0) red[1][wid] = ss;
    __syncthreads();
    float vtot = 0.f;
    #pragma unroll
    for (int w = 0; w < 8; ++w) vtot += red[1][w];
    float rstd = rsqrtf(vtot * (1.0f / TT) + EPS_LN);
    float o = d * rstd * g[t] + bia[t];
    _Float16 hv = (_Float16)o;
    Y[idx] = hv;
    Ylo[idx] = (_Float16)(o - (float)hv);
}

// ------- layernorm (fp32 in, f16 out, optional f16 lo residual), wave per row -------
template <bool LO>
__global__ __launch_bounds__(256) void ln_kernel(
    const float* __restrict__ X, const float* __restrict__ g,
    const float* __restrict__ bia, _Float16* __restrict__ Y,
    _Float16* __restrict__ Ylo) {
    int lane = threadIdx.x & 63;
    int row  = blockIdx.x * 4 + (threadIdx.x >> 6);
    const float* xr = X + (size_t)row * TT;
    float v[8];
    {
        float4 a = *(const float4*)(xr + lane * 8);
        float4 c = *(const float4*)(xr + lane * 8 + 4);
        v[0]=a.x; v[1]=a.y; v[2]=a.z; v[3]=a.w;
        v[4]=c.x; v[5]=c.y; v[6]=c.z; v[7]=c.w;
    }
    float s = 0.f;
    #pragma unroll
    for (int i = 0; i < 8; ++i) s += v[i];
    #pragma unroll
    for (int off = 32; off > 0; off >>= 1) s += __shfl_down(s, off);
    float mean = __shfl(s, 0) * (1.0f / TT);
    float ss = 0.f;
    #pragma unroll
    for (int i = 0; i < 8; ++i) { float d = v[i] - mean; ss = fmaf(d, d, ss); }
    #pragma unroll
    for (int off = 32; off > 0; off >>= 1) ss += __shfl_down(ss, off);
    float var  = __shfl(ss, 0) * (1.0f / TT);
    float rstd = rsqrtf(var + EPS_LN);
    half8 hv, lv;
    #pragma unroll
    for (int i = 0; i < 8; ++i) {
        int t = lane * 8 + i;
        float o = (v[i] - mean) * rstd * g[t] + bia[t];
        hv[i] = (_Float16)o;
        if (LO) lv[i] = (_Float16)(o - (float)hv[i]);
    }
    *(half8*)(Y + (size_t)row * TT + lane * 8) = hv;
    if (LO) *(half8*)(Ylo + (size_t)row * TT + lane * 8) = lv;
}

// ========== unified deep-pipelined MFMA GEMM (T3+T4+T5): C = act(A@W^T + b) (+R) =====
// R10: REVERTED to the R8-exact 16x16x32 configuration (742.4us best).
// R9 falsified the 32x32x16 switch on two counters: (1) SQ_LDS_BANK_CONFLICT
// 0 -> 2.1M -- 32 fragment rows cycle the period-4 XOR key twice -> 4-way
// conflicts; (2) w1's MINW=4 128-VGPR cap cannot hold 64-reg 32x32 accumulators
// -> scratch spill (31ms dispatch, VGPR=52, MfmaUtil 1.4%).
// Tile BM x BN, K-step BK=32, WGM x WGN waves, mfma 16x16x32.
// LDS ring of NBUF K-tile buffers; D=NBUF-1 tiles in flight; steady-state counted
// s_waitcnt vmcnt((D-1)*LPT) -- NEVER drained in the main loop; ONE raw s_barrier
// per K-iter; setprio(1) around the MFMA clusters.
// MINW=4 + LDS<=80KB -> VGPR<=128 -> 2 blocks/CU (m114 cross-block overlap).
// R7 lesson: BK=64 (144KB, 1 block/CU) REGRESSED (m132) -- keep BK=32.
// Swizzle (CPR=4 chunks/row): stage chunk sl of row r from source chunk
// sl^((r>>1)&3); fragment read at slot ((ks*4+q)^((fr>>1)&3))*8 -> measured 0
// bank conflicts (R0-R8).
// SPLIT: acc = A@W + Alo@W + A@Wlo (near-fp32 from f16 inputs).
// ACT: 0=none, 1=silu_fast, 3=tanh_fast for cols<nsplit else none (fused mu|sig).
template <int BM, int BN, int BK, int WGM, int WGN, int NBUF, int MINW,
          bool SPLIT, int ACT, bool RESID, typename OutT>
__global__ __launch_bounds__(WGM * WGN * 64, MINW) void gemmdp_kernel(
    const _Float16* __restrict__ A, const _Float16* __restrict__ Alo,
    const _Float16* __restrict__ W, const _Float16* __restrict__ Wlo,
    const float* __restrict__ bias, const float* __restrict__ bias2,
    const float* __restrict__ R, OutT* __restrict__ C,
    int N, int K, int nsplit) {
    constexpr int THREADS = WGM * WGN * 64;
    constexpr int CPR  = BK / 8;                   // 16B chunks per row
    constexpr int NS   = SPLIT ? 2 : 1;
    constexpr int D    = NBUF - 1;
    constexpr int CH_A = NS * BM * CPR;
    constexpr int CH_T = NS * (BM + BN) * CPR;
    constexpr int LPT  = CH_T / THREADS;
    static_assert(CH_T % THREADS == 0 && CH_A % THREADS == 0, "staging split");
    constexpr int ABUF = NS * BM * BK;             // halves per buf (A region)
    constexpr int WBUF = NS * BN * BK;
    constexpr int WOFF = NBUF * ABUF;
    constexpr int WTM  = BM / WGM;
    constexpr int WTN  = BN / WGN;
    constexpr int MI   = WTM / 16;
    constexpr int NI   = WTN / 16;

    __shared__ alignas(16) _Float16 lds[NBUF * (ABUF + WBUF)];

    const int tid = threadIdx.x;
    const int m0  = blockIdx.x * BM;
    const int n0  = blockIdx.y * BN;

    const _Float16* Asrc[2] = {A, Alo};
    const _Float16* Wsrc[2] = {W, Wlo};

    // ---- staging plan (fully unrolled -> registers; per-j branch is uniform) ----
    const _Float16* gsrc[LPT];
    int off0[LPT], bstr[LPT];
    #pragma unroll
    for (int j = 0; j < LPT; ++j) {
        int idx = j * THREADS + tid;
        if (j * THREADS < CH_A) {                  // A chunk (compile-time per j)
            int s   = idx / (BM * CPR);
            int rc  = idx % (BM * CPR);
            int row = rc / CPR, sl = rc % CPR;
            int src = sl ^ ((row >> 1) & (CPR - 1));
            gsrc[j] = Asrc[s] + (size_t)(m0 + row) * K + src * 8;
            off0[j] = (s * BM + row) * BK + sl * 8;
            bstr[j] = ABUF;
        } else {                                   // W chunk
            int i2  = idx - CH_A;
            int s   = i2 / (BN * CPR);
            int rc  = i2 % (BN * CPR);
            int row = rc / CPR, sl = rc % CPR;
            int src = sl ^ ((row >> 1) & (CPR - 1));
            gsrc[j] = Wsrc[s] + (size_t)(n0 + row) * K + src * 8;
            off0[j] = WOFF + (s * BN + row) * BK + sl * 8;
            bstr[j] = WBUF;
        }
    }

    auto stage = [&](int buf, int k0) {
        #pragma unroll
        for (int j = 0; j < LPT; ++j)
            async16(&lds[off0[j] + buf * bstr[j]], gsrc[j] + k0);
    };

    // ---- fragment geometry ----
    const int wid  = tid >> 6;
    const int wr   = wid / WGN;
    const int wc   = wid % WGN;
    const int lane = tid & 63;
    const int fr   = lane & 15;
    const int q    = lane >> 4;
    const int hxor = (fr >> 1) & (CPR - 1);

    const f32x4 vzero = {0.f, 0.f, 0.f, 0.f};
    f32x4 acc[MI][NI];
    #pragma unroll
    for (int mi = 0; mi < MI; ++mi)
        #pragma unroll
        for (int ni = 0; ni < NI; ++ni) acc[mi][ni] = vzero;

    auto body = [&](int buf) {
        const int da = buf * ABUF;
        const int dw = WOFF + buf * WBUF;
        #pragma unroll
        for (int ks = 0; ks < BK / 32; ++ks) {
            const int swz = ((ks * 4 + q) ^ hxor) * 8;   // swizzled k-offset (halves)
            half8 a[NS][MI], b[NS][NI];
            #pragma unroll
            for (int s = 0; s < NS; ++s) {
                #pragma unroll
                for (int mi = 0; mi < MI; ++mi)
                    a[s][mi] = *(const half8*)&lds[da + (s * BM + wr * WTM + mi * 16 + fr) * BK + swz];
                #pragma unroll
                for (int ni = 0; ni < NI; ++ni)
                    b[s][ni] = *(const half8*)&lds[dw + (s * BN + wc * WTN + ni * 16 + fr) * BK + swz];
            }
            __builtin_amdgcn_s_setprio(1);
            #pragma unroll
            for (int mi = 0; mi < MI; ++mi)
                #pragma unroll
                for (int ni = 0; ni < NI; ++ni)
                    acc[mi][ni] = __builtin_amdgcn_mfma_f32_16x16x32_f16(
                        a[0][mi], b[0][ni], acc[mi][ni], 0, 0, 0);
            if (SPLIT) {
                #pragma unroll
                for (int mi = 0; mi < MI; ++mi)
                    #pragma unroll
                    for (int ni = 0; ni < NI; ++ni)
                        acc[mi][ni] = __builtin_amdgcn_mfma_f32_16x16x32_f16(
                            a[1][mi], b[0][ni], acc[mi][ni], 0, 0, 0);
                #pragma unroll
                for (int mi = 0; mi < MI; ++mi)
                    #pragma unroll
                    for (int ni = 0; ni < NI; ++ni)
                        acc[mi][ni] = __builtin_amdgcn_mfma_f32_16x16x32_f16(
                            a[0][mi], b[1][ni], acc[mi][ni], 0, 0, 0);
            }
            __builtin_amdgcn_s_setprio(0);
        }
    };

    const int NK = K / BK;

    #pragma unroll
    for (int s = 0; s < D; ++s) stage(s, s * BK);

    int rbuf = 0, sbuf = D;
    for (int ki = 0; ki < NK - D; ++ki) {
        asm volatile("s_waitcnt vmcnt(%0)" :: "n"((D - 1) * LPT) : "memory");
        __builtin_amdgcn_s_barrier();
        asm volatile("" ::: "memory");
        stage(sbuf, (ki + D) * BK);
        sbuf = (sbuf + 1 == NBUF) ? 0 : sbuf + 1;
        body(rbuf);
        rbuf = (rbuf + 1 == NBUF) ? 0 : rbuf + 1;
    }
    if constexpr (D >= 4) {
        asm volatile("s_waitcnt vmcnt(%0)" :: "n"(3 * LPT) : "memory");
        __builtin_amdgcn_s_barrier();
        asm volatile("" ::: "memory");
        body(rbuf);
        rbuf = (rbuf + 1 == NBUF) ? 0 : rbuf + 1;
    }
    if constexpr (D >= 3) {
        asm volatile("s_waitcnt vmcnt(%0)" :: "n"(2 * LPT) : "memory");
        __builtin_amdgcn_s_barrier();
        asm volatile("" ::: "memory");
        body(rbuf);
        rbuf = (rbuf + 1 == NBUF) ? 0 : rbuf + 1;
    }
    if constexpr (D >= 2) {
        asm volatile("s_waitcnt vmcnt(%0)" :: "n"(1 * LPT) : "memory");
        __builtin_amdgcn_s_barrier();
        asm volatile("" ::: "memory");
        body(rbuf);
        rbuf = (rbuf + 1 == NBUF) ? 0 : rbuf + 1;
    }
    asm volatile("s_waitcnt vmcnt(0)" ::: "memory");
    __builtin_amdgcn_s_barrier();
    asm volatile("" ::: "memory");
    body(rbuf);

    // ---- epilogue; C/D layout: col = lane&15, row = (lane>>4)*4 + reg ----
    const bool fh = (n0 < nsplit);                  // block-uniform half select
    const float* bp = fh ? bias : bias2;
    const int coff = fh ? 0 : nsplit;
    const int r0 = q * 4;
    #pragma unroll
    for (int mi = 0; mi < MI; ++mi) {
        #pragma unroll
        for (int ni = 0; ni < NI; ++ni) {
            const int col = n0 + wc * WTN + ni * 16 + fr;
            const float bv = bp[col - coff];
            #pragma unroll
            for (int r = 0; r < 4; ++r) {
                const int row = m0 + wr * WTM + mi * 16 + r0 + r;
                float v = acc[mi][ni][r] + bv;
                if (ACT == 1) v = silu_fast(v);
                if (ACT == 3 && fh) v = tanh_fast(v);
                if (RESID) v += R[(size_t)row * N + col];
                C[(size_t)row * N + col] = (OutT)v;
            }
        }
    }
}

// ==== fused attention update + layernorm: Q += sum_k S*H; h = LN(Q)*g+b -> f16 ====
__global__ __launch_bounds__(512) void attnln_kernel(
    float* __restrict__ Q, const float* __restrict__ MS,
    const float* __restrict__ x,
    const float* __restrict__ omega, const float* __restrict__ G,
    const float* __restrict__ phase,
    const float* __restrict__ g, const float* __restrict__ bia,
    _Float16* __restrict__ Y) {
    __shared__ float cs[8][516];
    __shared__ float gs[8][516];
    __shared__ float red[2][8];
    const int tid = threadIdx.x;
    const int b   = blockIdx.x;
    const float x0 = x[2 * b], x1 = x[2 * b + 1];
    #pragma unroll
    for (int it = 0; it < 8; ++it) {
        int j = it * 512 + tid;            // 0..4095 flat (t,k) index
        float2 om = *(const float2*)(omega + 2 * j);
        float arg = fmaf(om.x, x0, fmaf(om.y, x1, phase[j]));
        cs[j & 7][j >> 3] = __cosf(arg);
        gs[j & 7][j >> 3] = G[j];
    }
    __syncthreads();
    const int t = tid;
    float mu  = MS[(size_t)b * 1024 + t];
    float sig = MS[(size_t)b * 1024 + 512 + t];
    float inv = -0.5f * __builtin_amdgcn_rcpf(fmaf(sig, sig, EPS_SIG));
    float acc = 0.f;
    #pragma unroll
    for (int k = 0; k < 8; ++k) {
        float d = gs[k][t] - mu;
        acc = fmaf(__expf(d * d * inv), cs[k][t], acc);
    }
    const size_t idx = (size_t)b * TT + t;
    float qn = Q[idx] + acc;
    Q[idx] = qn;
    const int wid = tid >> 6, lane = tid & 63;
    float s = qn;
    #pragma unroll
    for (int off = 32; off > 0; off >>= 1) s += __shfl_down(s, off);
    if (lane == 0) red[0][wid] = s;
    __syncthreads();
    float tot = 0.f;
    #pragma unroll
    for (int w = 0; w < 8; ++w) tot += red[0][w];
    float mean = tot * (1.0f / TT);
    float d = qn - mean;
    float ss = d * d;
    #pragma unroll
    for (int off = 32; off > 0; off >>= 1) ss += __shfl_down(ss, off);
    if (lane == 0) red[1][wid] = ss;
    __syncthreads();
    float vtot = 0.f;
    #pragma unroll
    for (int w = 0; w < 8; ++w) vtot += red[1][w];
    float rstd = rsqrtf(vtot * (1.0f / TT) + EPS_LN);
    Y[idx] = (_Float16)(d * rstd * g[t] + bia[t]);
}

// ---------------- readout: out[b] = silu(Q[b,:]) . ro_w + ro_b ----------------
__global__ __launch_bounds__(256) void readout_kernel(
    const float* __restrict__ Q, const float* __restrict__ row_,
    const float* __restrict__ rob, float* __restrict__ out) {
    int lane = threadIdx.x & 63;
    int row  = blockIdx.x * 4 + (threadIdx.x >> 6);
    const float* qr = Q + (size_t)row * TT;
    float acc = 0.f;
    #pragma unroll
    for (int i = 0; i < 8; ++i) {
        int t = lane * 8 + i;
        acc = fmaf(silu_f(qr[t]), row_[t], acc);
    }
    #pragma unroll
    for (int off = 32; off > 0; off >>= 1) acc += __shfl_down(acc, off);
    if (lane == 0) out[row] = acc + rob[0];
}

} // namespace

extern "C" void kernel_launch(void* const* d_in, const int* in_sizes, int n_in,
                              void* d_out, int out_size, void* d_ws, size_t ws_size,
                              hipStream_t stream) {
    const float* x     = (const float*)d_in[0];
    const float* omega = (const float*)d_in[1];
    const float* G     = (const float*)d_in[2];
    const float* phase = (const float*)d_in[3];
    const float* l1_w  = (const float*)d_in[4];
    const float* l1_b  = (const float*)d_in[5];
    const float* mu_w  = (const float*)d_in[6];
    const float* mu_b  = (const float*)d_in[7];
    const float* sg_w  = (const float*)d_in[8];
    const float* sg_b  = (const float*)d_in[9];
    const float* alqg  = (const float*)d_in[10];
    const float* alqb  = (const float*)d_in[11];
    const float* alfg  = (const float*)d_in[12];
    const float* alfb  = (const float*)d_in[13];
    const float* a_w1  = (const float*)d_in[14];
    const float* a_b1  = (const float*)d_in[15];
    const float* a_w2  = (const float*)d_in[16];
    const float* a_b2  = (const float*)d_in[17];
    const float* mln_g = (const float*)d_in[18];
    const float* mln_b = (const float*)d_in[19];
    const float* m_w1  = (const float*)d_in[20];
    const float* m_b1  = (const float*)d_in[21];
    const float* m_w2  = (const float*)d_in[22];
    const float* m_b2  = (const float*)d_in[23];
    const float* ro_w  = (const float*)d_in[24];
    const float* ro_b  = (const float*)d_in[25];

    // ---- workspace layout (total 100,663,296 B == round-1 proven footprint) ----
    char* ws = (char*)d_ws;
    float*     Q    = (float*)ws;                          // 16 MB  [B,T] fp32
    _Float16*  h_hi = (_Float16*)(ws + 16777216);          //  8 MB  [B,T] f16
    _Float16*  h_lo = (_Float16*)(ws + 25165824);          //  8 MB  [B,T] f16
    _Float16*  mid  = (_Float16*)(ws + 33554432);          // 32 MB  [B,F] f16
    float*     MS   = (float*)(ws + 33554432);             // alias on mid: [B,1024] fp32
    _Float16*  wbuf = (_Float16*)(ws + 67108864);          // 32 MB  f16 weights

    _Float16* msw_hi = wbuf;                     // 4*1024*512 (mu/sig concat)
    _Float16* msw_lo = msw_hi + 2097152;
    _Float16* aw1    = msw_lo + 2097152;         // 4*2048*512
    _Float16* aw2    = aw1 + 4194304;
    _Float16* mw1    = aw2 + 4194304;            // 2*2048*512
    _Float16* mw2    = mw1 + 2097152;

    dim3 blk(256);
    const int BIG = 1 << 30;

    // merged weight conversion (re-done every call; inputs re-poisoned by harness)
    cvtall_kernel<<<14336, blk, 0, stream>>>(
        mu_w, sg_w, a_w1, a_w2, m_w1, m_w2,
        msw_hi, msw_lo, aw1, aw2, mw1, mw2);

    // fused tokenizer + layer-0 LN (hi+lo)
    tokln_kernel<<<BB, dim3(512), 0, stream>>>(
        x, l1_w, l1_b, alqg, alqb, Q, h_hi, h_lo);

    for (int i = 0; i < 4; ++i) {
        if (i > 0)
            ln_kernel<true><<<BB / 4, blk, 0, stream>>>(
                Q, alqg + i * TT, alqb + i * TT, h_hi, h_lo);
        // fused mu|sig SPLIT GEMM: N=1024, deep pipeline, tanh on mu half only
        gemmdp_kernel<256, 128, 32, 4, 2, 3, 2, true, 3, false, float>
            <<<dim3(BB / 256, 1024 / 128), dim3(512), 0, stream>>>(
            h_hi, h_lo, msw_hi + (size_t)i * 524288, msw_lo + (size_t)i * 524288,
            mu_b + i * TT, sg_b + i * TT, nullptr, MS, 1024, TT, TT);
        // fused attention update + LN -> h_hi
        attnln_kernel<<<BB, dim3(512), 0, stream>>>(
            Q, MS, x, omega, G, phase, alfg + i * TT, alfb + i * TT, h_hi);
        // w1: BK=32, 72KB LDS, MINW=4 -> 2 blocks/CU
        gemmdp_kernel<256, 128, 32, 4, 2, 3, 4, false, 1, false, _Float16>
            <<<dim3(BB / 256, FF / 128), dim3(512), 0, stream>>>(
            h_hi, nullptr, aw1 + (size_t)i * 1048576, nullptr,
            a_b1 + i * FF, a_b1 + i * FF, nullptr, mid, FF, TT, BIG);
        // w2: NBUF=5 (80KB x 2 blocks/CU), D=4 lead
        gemmdp_kernel<128, 128, 32, 2, 4, 5, 4, false, 0, true, float>
            <<<dim3(BB / 128, TT / 128), dim3(512), 0, stream>>>(
            mid, nullptr, aw2 + (size_t)i * 1048576, nullptr,
            a_b2 + i * TT, a_b2 + i * TT, Q, Q, TT, FF, BIG);
    }
    for (int i = 0; i < 2; ++i) {
        ln_kernel<false><<<BB / 4, blk, 0, stream>>>(
            Q, mln_g + i * TT, mln_b + i * TT, h_hi, nullptr);
        gemmdp_kernel<256, 128, 32, 4, 2, 3, 4, false, 1, false, _Float16>
            <<<dim3(BB / 256, FF / 128), dim3(512), 0, stream>>>(
            h_hi, nullptr, mw1 + (size_t)i * 1048576, nullptr,
            m_b1 + i * FF, m_b1 + i * FF, nullptr, mid, FF, TT, BIG);
        gemmdp_kernel<128, 128, 32, 2, 4, 5, 4, false, 0, true, float>
            <<<dim3(BB / 128, TT / 128), dim3(512), 0, stream>>>(
            mid, nullptr, mw2 + (size_t)i * 1048576, nullptr,
            m_b2 + i * TT, m_b2 + i * TT, Q, Q, TT, FF, BIG);
    }

    readout_kernel<<<BB / 4, blk, 0, stream>>>(Q, ro_w, ro_b, (float*)d_out);
}

// Round 11
// 723.753 us; speedup vs baseline: 1.1853x; 1.0196x over previous
//
#include <hip/hip_runtime.h>
#include <cmath>

namespace {

constexpr int BB = 8192;
constexpr int TT = 512;
constexpr int FF = 2048;
constexpr float EPS_LN  = 1e-5f;
constexpr float EPS_SIG = 1e-8f;

typedef _Float16 half8 __attribute__((ext_vector_type(8)));
typedef _Float16 half4 __attribute__((ext_vector_type(4)));
typedef float f32x4 __attribute__((ext_vector_type(4)));

typedef __attribute__((address_space(1))) void gvoid_t;
typedef __attribute__((address_space(3))) void lvoid_t;

__device__ __forceinline__ void async16(void* lds, const void* g) {
    __builtin_amdgcn_global_load_lds((gvoid_t*)g, (lvoid_t*)lds, 16, 0, 0);
}

__device__ __forceinline__ float silu_f(float v) {
    return v / (1.0f + expf(-v));
}
// fast silu: only for f16-rounded outputs (error ~1e-6 << f16 ulp)
__device__ __forceinline__ float silu_fast(float v) {
    return v * __builtin_amdgcn_rcpf(1.0f + __expf(-v));
}
// fast tanh: (e^{2v}-1)/(e^{2v}+1); clamp +-10 (exact: tanh saturates ~9.01 in f32)
__device__ __forceinline__ float tanh_fast(float v) {
    float t = __expf(2.0f * fminf(fmaxf(v, -10.0f), 10.0f));
    return (t - 1.0f) * __builtin_amdgcn_rcpf(t + 1.0f);
}

// ===== merged weight conversion: all 6 fp32->f16 conversions in ONE dispatch =====
__global__ __launch_bounds__(256) void cvtall_kernel(
    const float* __restrict__ mu_w, const float* __restrict__ sg_w,
    const float* __restrict__ a_w1, const float* __restrict__ a_w2,
    const float* __restrict__ m_w1, const float* __restrict__ m_w2,
    _Float16* __restrict__ msw_hi, _Float16* __restrict__ msw_lo,
    _Float16* __restrict__ aw1, _Float16* __restrict__ aw2,
    _Float16* __restrict__ mw1, _Float16* __restrict__ mw2) {
    int i = (blockIdx.x * 256 + threadIdx.x) * 4;     // < 14,680,064
    if (i < 2097152) {                                 // mu|sig cvtcat (hi+lo)
        const float* s; int base, ii = i;
        if (i < 1048576) { s = mu_w; base = 0; }
        else             { s = sg_w; base = 262144; ii -= 1048576; }
        int dst = ((ii >> 18) << 19) + base + (ii & 262143);
        float4 v = *(const float4*)(s + ii);
        half4 h, l;
        h[0] = (_Float16)v.x; h[1] = (_Float16)v.y;
        h[2] = (_Float16)v.z; h[3] = (_Float16)v.w;
        l[0] = (_Float16)(v.x - (float)h[0]);
        l[1] = (_Float16)(v.y - (float)h[1]);
        l[2] = (_Float16)(v.z - (float)h[2]);
        l[3] = (_Float16)(v.w - (float)h[3]);
        *(half4*)(msw_hi + dst) = h;
        *(half4*)(msw_lo + dst) = l;
        return;
    }
    const float* s; _Float16* d; int ii;
    if      (i <  6291456) { s = a_w1; d = aw1; ii = i -  2097152; }
    else if (i < 10485760) { s = a_w2; d = aw2; ii = i -  6291456; }
    else if (i < 12582912) { s = m_w1; d = mw1; ii = i - 10485760; }
    else                   { s = m_w2; d = mw2; ii = i - 12582912; }
    float4 v = *(const float4*)(s + ii);
    half4 h;
    h[0] = (_Float16)v.x; h[1] = (_Float16)v.y;
    h[2] = (_Float16)v.z; h[3] = (_Float16)v.w;
    *(half4*)(d + ii) = h;
}

// ==== fused tokenizer + first layernorm: Q = silu(x@l1), h = LN(Q)*g+b (hi+lo) ====
__global__ __launch_bounds__(512) void tokln_kernel(
    const float* __restrict__ x, const float* __restrict__ l1w,
    const float* __restrict__ l1b,
    const float* __restrict__ g, const float* __restrict__ bia,
    float* __restrict__ Q, _Float16* __restrict__ Y, _Float16* __restrict__ Ylo) {
    __shared__ float red[2][8];
    const int tid = threadIdx.x, b = blockIdx.x, t = tid;
    const float x0 = x[2 * b], x1 = x[2 * b + 1];
    float qn = silu_f(fmaf(x0, l1w[2 * t], fmaf(x1, l1w[2 * t + 1], l1b[t])));
    const size_t idx = (size_t)b * TT + t;
    Q[idx] = qn;
    const int wid = tid >> 6, lane = tid & 63;
    float s = qn;
    #pragma unroll
    for (int off = 32; off > 0; off >>= 1) s += __shfl_down(s, off);
    if (lane == 0) red[0][wid] = s;
    __syncthreads();
    float tot = 0.f;
    #pragma unroll
    for (int w = 0; w < 8; ++w) tot += red[0][w];
    float mean = tot * (1.0f / TT);
    float d = qn - mean;
    float ss = d * d;
    #pragma unroll
    for (int off = 32; off > 0; off >>= 1) ss += __shfl_down(ss, off);
    if (lane == 0) red[1][wid] = ss;
    __syncthreads();
    float vtot = 0.f;
    #pragma unroll
    for (int w = 0; w < 8; ++w) vtot += red[1][w];
    float rstd = rsqrtf(vtot * (1.0f / TT) + EPS_LN);
    float o = d * rstd * g[t] + bia[t];
    _Float16 hv = (_Float16)o;
    Y[idx] = hv;
    Ylo[idx] = (_Float16)(o - (float)hv);
}

// ------- layernorm (fp32 in, f16 out, optional f16 lo residual), wave per row -------
template <bool LO>
__global__ __launch_bounds__(256) void ln_kernel(
    const float* __restrict__ X, const float* __restrict__ g,
    const float* __restrict__ bia, _Float16* __restrict__ Y,
    _Float16* __restrict__ Ylo) {
    int lane = threadIdx.x & 63;
    int row  = blockIdx.x * 4 + (threadIdx.x >> 6);
    const float* xr = X + (size_t)row * TT;
    float v[8];
    {
        float4 a = *(const float4*)(xr + lane * 8);
        float4 c = *(const float4*)(xr + lane * 8 + 4);
        v[0]=a.x; v[1]=a.y; v[2]=a.z; v[3]=a.w;
        v[4]=c.x; v[5]=c.y; v[6]=c.z; v[7]=c.w;
    }
    float s = 0.f;
    #pragma unroll
    for (int i = 0; i < 8; ++i) s += v[i];
    #pragma unroll
    for (int off = 32; off > 0; off >>= 1) s += __shfl_down(s, off);
    float mean = __shfl(s, 0) * (1.0f / TT);
    float ss = 0.f;
    #pragma unroll
    for (int i = 0; i < 8; ++i) { float d = v[i] - mean; ss = fmaf(d, d, ss); }
    #pragma unroll
    for (int off = 32; off > 0; off >>= 1) ss += __shfl_down(ss, off);
    float var  = __shfl(ss, 0) * (1.0f / TT);
    float rstd = rsqrtf(var + EPS_LN);
    half8 hv, lv;
    #pragma unroll
    for (int i = 0; i < 8; ++i) {
        int t = lane * 8 + i;
        float o = (v[i] - mean) * rstd * g[t] + bia[t];
        hv[i] = (_Float16)o;
        if (LO) lv[i] = (_Float16)(o - (float)hv[i]);
    }
    *(half8*)(Y + (size_t)row * TT + lane * 8) = hv;
    if (LO) *(half8*)(Ylo + (size_t)row * TT + lane * 8) = lv;
}

// ====== R11: 8-phase-style deep-pipelined 256x256 GEMM for w1 (T3+T4+T5, m201) ======
// 512 thr = 8 waves (2M x 4N), wave out 128x64 (MI=8, NI=4), BK=32, NK=16.
// LDS ring NBUF=4 x (A 256x32 + W 256x32) f16 = 128 KB (R3's proven hazard layout).
// Per K-iter: head {vmcnt(8) counted -- tiles t+1,t+2 stay in flight; barrier},
// then 4 PHASES: {ds_read a-pair (+4xb in phase 0) || stage 1 load of tile t+3 ->
// barrier -> setprio(1) 8 MFMA setprio(0) -> barrier}. Every barrier window mixes
// ds_read + stage + MFMA work from 8 waves (the m196/m218 mechanism); vmcnt never
// drains mid-loop. Hazards: stage(t+3)->buf(t-1)&3 whose reads were MFMA-consumed
// before each phase's trailing barrier of iter t-1; reads of tile t covered by own
// vmcnt(8) + head barrier. Barrier count uniform (no divergent barriers).
// Epilogue peel: vmcnt(8)/vmcnt(4)/vmcnt(0) for the last 3 iters.
__global__ __launch_bounds__(512, 2) void gemm8p_kernel(
    const _Float16* __restrict__ A, const _Float16* __restrict__ W,
    const float* __restrict__ bias, _Float16* __restrict__ C, int N, int K) {
    constexpr int BM = 256, BN = 256, BK = 32, NBUF = 4;
    constexpr int ABUF = BM * BK;            // 8192 halves (== WBUF)
    constexpr int WOFF = NBUF * ABUF;

    __shared__ alignas(16) _Float16 lds[2 * NBUF * ABUF];   // 131072 B

    const int tid = threadIdx.x;
    const int m0  = blockIdx.x * BM;
    const int n0  = blockIdx.y * BN;

    // staging plan: 2048 16B-chunks; j=0,1 -> A halves; j=2,3 -> W halves.
    // chunk: row = (idx&1023)>>2, slot = idx&3, source chunk = slot^((row>>1)&3).
    const _Float16* gsrc[4];
    int off0[4];
    #pragma unroll
    for (int j = 0; j < 4; ++j) {
        int idx = j * 512 + tid;
        int isW = idx >> 10;
        int ch  = idx & 1023;
        int row = ch >> 2, sl = ch & 3;
        int src = sl ^ ((row >> 1) & 3);
        gsrc[j] = (isW ? W + (size_t)(n0 + row) * K
                       : A + (size_t)(m0 + row) * K) + src * 8;
        off0[j] = isW * WOFF + row * BK + sl * 8;
    }
    auto stage1 = [&](int buf, int k0, int j) {
        async16(&lds[off0[j] + buf * ABUF], gsrc[j] + k0);
    };

    // fragment geometry (16x16x32)
    const int wid  = tid >> 6;
    const int wr   = wid >> 2;               // 0..1
    const int wc   = wid & 3;                // 0..3
    const int lane = tid & 63;
    const int fr   = lane & 15;
    const int q    = lane >> 4;
    const int swz  = (q ^ ((fr >> 1) & 3)) * 8;

    const _Float16* aB = &lds[(wr * 128 + fr) * BK + swz];
    const _Float16* wB = &lds[WOFF + (wc * 64 + fr) * BK + swz];

    f32x4 acc[8][4];
    #pragma unroll
    for (int mi = 0; mi < 8; ++mi)
        #pragma unroll
        for (int ni = 0; ni < 4; ++ni) acc[mi][ni] = {0.f, 0.f, 0.f, 0.f};

    const int NK = K / BK;                   // 16

    // prologue: 3 tiles in flight (12 loads)
    #pragma unroll
    for (int s = 0; s < 3; ++s)
        #pragma unroll
        for (int j = 0; j < 4; ++j) stage1(s, s * BK, j);

    for (int t = 0; t < NK; ++t) {
        const int d = (t & 3) * ABUF;
        if (t < NK - 2)       { asm volatile("s_waitcnt vmcnt(8)" ::: "memory"); }
        else if (t == NK - 2) { asm volatile("s_waitcnt vmcnt(4)" ::: "memory"); }
        else                  { asm volatile("s_waitcnt vmcnt(0)" ::: "memory"); }
        __builtin_amdgcn_s_barrier();
        asm volatile("" ::: "memory");
        const bool st = (t < NK - 3);        // block-uniform
        half8 b0 = *(const half8*)(wB + d);
        half8 b1 = *(const half8*)(wB + d + 16 * BK);
        half8 b2 = *(const half8*)(wB + d + 32 * BK);
        half8 b3 = *(const half8*)(wB + d + 48 * BK);
        #pragma unroll
        for (int p = 0; p < 4; ++p) {
            half8 a0 = *(const half8*)(aB + d + (2 * p)     * 16 * BK);
            half8 a1 = *(const half8*)(aB + d + (2 * p + 1) * 16 * BK);
            if (st) stage1((t + 3) & 3, (t + 3) * BK, p);
            __builtin_amdgcn_s_barrier();
            asm volatile("" ::: "memory");
            __builtin_amdgcn_s_setprio(1);
            acc[2*p][0]   = __builtin_amdgcn_mfma_f32_16x16x32_f16(a0, b0, acc[2*p][0],   0, 0, 0);
            acc[2*p][1]   = __builtin_amdgcn_mfma_f32_16x16x32_f16(a0, b1, acc[2*p][1],   0, 0, 0);
            acc[2*p][2]   = __builtin_amdgcn_mfma_f32_16x16x32_f16(a0, b2, acc[2*p][2],   0, 0, 0);
            acc[2*p][3]   = __builtin_amdgcn_mfma_f32_16x16x32_f16(a0, b3, acc[2*p][3],   0, 0, 0);
            acc[2*p+1][0] = __builtin_amdgcn_mfma_f32_16x16x32_f16(a1, b0, acc[2*p+1][0], 0, 0, 0);
            acc[2*p+1][1] = __builtin_amdgcn_mfma_f32_16x16x32_f16(a1, b1, acc[2*p+1][1], 0, 0, 0);
            acc[2*p+1][2] = __builtin_amdgcn_mfma_f32_16x16x32_f16(a1, b2, acc[2*p+1][2], 0, 0, 0);
            acc[2*p+1][3] = __builtin_amdgcn_mfma_f32_16x16x32_f16(a1, b3, acc[2*p+1][3], 0, 0, 0);
            __builtin_amdgcn_s_setprio(0);
            __builtin_amdgcn_s_barrier();
            asm volatile("" ::: "memory");
        }
    }

    // epilogue: C/D col = lane&15, row = (lane>>4)*4 + reg
    const int r0 = q * 4;
    #pragma unroll
    for (int mi = 0; mi < 8; ++mi) {
        #pragma unroll
        for (int ni = 0; ni < 4; ++ni) {
            const int col = n0 + wc * 64 + ni * 16 + fr;
            const float bv = bias[col];
            #pragma unroll
            for (int r = 0; r < 4; ++r) {
                const int row = m0 + wr * 128 + mi * 16 + r0 + r;
                C[(size_t)row * N + col] = (_Float16)silu_fast(acc[mi][ni][r] + bv);
            }
        }
    }
}

// ========== unified deep-pipelined MFMA GEMM (coarse ring; musig + w2) ==========
// R10-exact configuration (742us-lineage best). 16x16x32, BK=32, counted vmcnt,
// one barrier per K-iter, setprio around MFMA clusters.
template <int BM, int BN, int BK, int WGM, int WGN, int NBUF, int MINW,
          bool SPLIT, int ACT, bool RESID, typename OutT>
__global__ __launch_bounds__(WGM * WGN * 64, MINW) void gemmdp_kernel(
    const _Float16* __restrict__ A, const _Float16* __restrict__ Alo,
    const _Float16* __restrict__ W, const _Float16* __restrict__ Wlo,
    const float* __restrict__ bias, const float* __restrict__ bias2,
    const float* __restrict__ R, OutT* __restrict__ C,
    int N, int K, int nsplit) {
    constexpr int THREADS = WGM * WGN * 64;
    constexpr int CPR  = BK / 8;                   // 16B chunks per row
    constexpr int NS   = SPLIT ? 2 : 1;
    constexpr int D    = NBUF - 1;
    constexpr int CH_A = NS * BM * CPR;
    constexpr int CH_T = NS * (BM + BN) * CPR;
    constexpr int LPT  = CH_T / THREADS;
    static_assert(CH_T % THREADS == 0 && CH_A % THREADS == 0, "staging split");
    constexpr int ABUF = NS * BM * BK;             // halves per buf (A region)
    constexpr int WBUF = NS * BN * BK;
    constexpr int WOFF = NBUF * ABUF;
    constexpr int WTM  = BM / WGM;
    constexpr int WTN  = BN / WGN;
    constexpr int MI   = WTM / 16;
    constexpr int NI   = WTN / 16;

    __shared__ alignas(16) _Float16 lds[NBUF * (ABUF + WBUF)];

    const int tid = threadIdx.x;
    const int m0  = blockIdx.x * BM;
    const int n0  = blockIdx.y * BN;

    const _Float16* Asrc[2] = {A, Alo};
    const _Float16* Wsrc[2] = {W, Wlo};

    const _Float16* gsrc[LPT];
    int off0[LPT], bstr[LPT];
    #pragma unroll
    for (int j = 0; j < LPT; ++j) {
        int idx = j * THREADS + tid;
        if (j * THREADS < CH_A) {
            int s   = idx / (BM * CPR);
            int rc  = idx % (BM * CPR);
            int row = rc / CPR, sl = rc % CPR;
            int src = sl ^ ((row >> 1) & (CPR - 1));
            gsrc[j] = Asrc[s] + (size_t)(m0 + row) * K + src * 8;
            off0[j] = (s * BM + row) * BK + sl * 8;
            bstr[j] = ABUF;
        } else {
            int i2  = idx - CH_A;
            int s   = i2 / (BN * CPR);
            int rc  = i2 % (BN * CPR);
            int row = rc / CPR, sl = rc % CPR;
            int src = sl ^ ((row >> 1) & (CPR - 1));
            gsrc[j] = Wsrc[s] + (size_t)(n0 + row) * K + src * 8;
            off0[j] = WOFF + (s * BN + row) * BK + sl * 8;
            bstr[j] = WBUF;
        }
    }

    auto stage = [&](int buf, int k0) {
        #pragma unroll
        for (int j = 0; j < LPT; ++j)
            async16(&lds[off0[j] + buf * bstr[j]], gsrc[j] + k0);
    };

    const int wid  = tid >> 6;
    const int wr   = wid / WGN;
    const int wc   = wid % WGN;
    const int lane = tid & 63;
    const int fr   = lane & 15;
    const int q    = lane >> 4;
    const int hxor = (fr >> 1) & (CPR - 1);

    const f32x4 vzero = {0.f, 0.f, 0.f, 0.f};
    f32x4 acc[MI][NI];
    #pragma unroll
    for (int mi = 0; mi < MI; ++mi)
        #pragma unroll
        for (int ni = 0; ni < NI; ++ni) acc[mi][ni] = vzero;

    auto body = [&](int buf) {
        const int da = buf * ABUF;
        const int dw = WOFF + buf * WBUF;
        #pragma unroll
        for (int ks = 0; ks < BK / 32; ++ks) {
            const int swz = ((ks * 4 + q) ^ hxor) * 8;
            half8 a[NS][MI], b[NS][NI];
            #pragma unroll
            for (int s = 0; s < NS; ++s) {
                #pragma unroll
                for (int mi = 0; mi < MI; ++mi)
                    a[s][mi] = *(const half8*)&lds[da + (s * BM + wr * WTM + mi * 16 + fr) * BK + swz];
                #pragma unroll
                for (int ni = 0; ni < NI; ++ni)
                    b[s][ni] = *(const half8*)&lds[dw + (s * BN + wc * WTN + ni * 16 + fr) * BK + swz];
            }
            __builtin_amdgcn_s_setprio(1);
            #pragma unroll
            for (int mi = 0; mi < MI; ++mi)
                #pragma unroll
                for (int ni = 0; ni < NI; ++ni)
                    acc[mi][ni] = __builtin_amdgcn_mfma_f32_16x16x32_f16(
                        a[0][mi], b[0][ni], acc[mi][ni], 0, 0, 0);
            if (SPLIT) {
                #pragma unroll
                for (int mi = 0; mi < MI; ++mi)
                    #pragma unroll
                    for (int ni = 0; ni < NI; ++ni)
                        acc[mi][ni] = __builtin_amdgcn_mfma_f32_16x16x32_f16(
                            a[1][mi], b[0][ni], acc[mi][ni], 0, 0, 0);
                #pragma unroll
                for (int mi = 0; mi < MI; ++mi)
                    #pragma unroll
                    for (int ni = 0; ni < NI; ++ni)
                        acc[mi][ni] = __builtin_amdgcn_mfma_f32_16x16x32_f16(
                            a[0][mi], b[1][ni], acc[mi][ni], 0, 0, 0);
            }
            __builtin_amdgcn_s_setprio(0);
        }
    };

    const int NK = K / BK;

    #pragma unroll
    for (int s = 0; s < D; ++s) stage(s, s * BK);

    int rbuf = 0, sbuf = D;
    for (int ki = 0; ki < NK - D; ++ki) {
        asm volatile("s_waitcnt vmcnt(%0)" :: "n"((D - 1) * LPT) : "memory");
        __builtin_amdgcn_s_barrier();
        asm volatile("" ::: "memory");
        stage(sbuf, (ki + D) * BK);
        sbuf = (sbuf + 1 == NBUF) ? 0 : sbuf + 1;
        body(rbuf);
        rbuf = (rbuf + 1 == NBUF) ? 0 : rbuf + 1;
    }
    if constexpr (D >= 4) {
        asm volatile("s_waitcnt vmcnt(%0)" :: "n"(3 * LPT) : "memory");
        __builtin_amdgcn_s_barrier();
        asm volatile("" ::: "memory");
        body(rbuf);
        rbuf = (rbuf + 1 == NBUF) ? 0 : rbuf + 1;
    }
    if constexpr (D >= 3) {
        asm volatile("s_waitcnt vmcnt(%0)" :: "n"(2 * LPT) : "memory");
        __builtin_amdgcn_s_barrier();
        asm volatile("" ::: "memory");
        body(rbuf);
        rbuf = (rbuf + 1 == NBUF) ? 0 : rbuf + 1;
    }
    if constexpr (D >= 2) {
        asm volatile("s_waitcnt vmcnt(%0)" :: "n"(1 * LPT) : "memory");
        __builtin_amdgcn_s_barrier();
        asm volatile("" ::: "memory");
        body(rbuf);
        rbuf = (rbuf + 1 == NBUF) ? 0 : rbuf + 1;
    }
    asm volatile("s_waitcnt vmcnt(0)" ::: "memory");
    __builtin_amdgcn_s_barrier();
    asm volatile("" ::: "memory");
    body(rbuf);

    const bool fh = (n0 < nsplit);
    const float* bp = fh ? bias : bias2;
    const int coff = fh ? 0 : nsplit;
    const int r0 = q * 4;
    #pragma unroll
    for (int mi = 0; mi < MI; ++mi) {
        #pragma unroll
        for (int ni = 0; ni < NI; ++ni) {
            const int col = n0 + wc * WTN + ni * 16 + fr;
            const float bv = bp[col - coff];
            #pragma unroll
            for (int r = 0; r < 4; ++r) {
                const int row = m0 + wr * WTM + mi * 16 + r0 + r;
                float v = acc[mi][ni][r] + bv;
                if (ACT == 1) v = silu_fast(v);
                if (ACT == 3 && fh) v = tanh_fast(v);
                if (RESID) v += R[(size_t)row * N + col];
                C[(size_t)row * N + col] = (OutT)v;
            }
        }
    }
}

// ==== fused attention update + layernorm: Q += sum_k S*H; h = LN(Q)*g+b -> f16 ====
__global__ __launch_bounds__(512) void attnln_kernel(
    float* __restrict__ Q, const float* __restrict__ MS,
    const float* __restrict__ x,
    const float* __restrict__ omega, const float* __restrict__ G,
    const float* __restrict__ phase,
    const float* __restrict__ g, const float* __restrict__ bia,
    _Float16* __restrict__ Y) {
    __shared__ float cs[8][516];
    __shared__ float gs[8][516];
    __shared__ float red[2][8];
    const int tid = threadIdx.x;
    const int b   = blockIdx.x;
    const float x0 = x[2 * b], x1 = x[2 * b + 1];
    #pragma unroll
    for (int it = 0; it < 8; ++it) {
        int j = it * 512 + tid;            // 0..4095 flat (t,k) index
        float2 om = *(const float2*)(omega + 2 * j);
        float arg = fmaf(om.x, x0, fmaf(om.y, x1, phase[j]));
        cs[j & 7][j >> 3] = __cosf(arg);
        gs[j & 7][j >> 3] = G[j];
    }
    __syncthreads();
    const int t = tid;
    float mu  = MS[(size_t)b * 1024 + t];
    float sig = MS[(size_t)b * 1024 + 512 + t];
    float inv = -0.5f * __builtin_amdgcn_rcpf(fmaf(sig, sig, EPS_SIG));
    float acc = 0.f;
    #pragma unroll
    for (int k = 0; k < 8; ++k) {
        float d = gs[k][t] - mu;
        acc = fmaf(__expf(d * d * inv), cs[k][t], acc);
    }
    const size_t idx = (size_t)b * TT + t;
    float qn = Q[idx] + acc;
    Q[idx] = qn;
    const int wid = tid >> 6, lane = tid & 63;
    float s = qn;
    #pragma unroll
    for (int off = 32; off > 0; off >>= 1) s += __shfl_down(s, off);
    if (lane == 0) red[0][wid] = s;
    __syncthreads();
    float tot = 0.f;
    #pragma unroll
    for (int w = 0; w < 8; ++w) tot += red[0][w];
    float mean = tot * (1.0f / TT);
    float d = qn - mean;
    float ss = d * d;
    #pragma unroll
    for (int off = 32; off > 0; off >>= 1) ss += __shfl_down(ss, off);
    if (lane == 0) red[1][wid] = ss;
    __syncthreads();
    float vtot = 0.f;
    #pragma unroll
    for (int w = 0; w < 8; ++w) vtot += red[1][w];
    float rstd = rsqrtf(vtot * (1.0f / TT) + EPS_LN);
    Y[idx] = (_Float16)(d * rstd * g[t] + bia[t]);
}

// ---------------- readout: out[b] = silu(Q[b,:]) . ro_w + ro_b ----------------
__global__ __launch_bounds__(256) void readout_kernel(
    const float* __restrict__ Q, const float* __restrict__ row_,
    const float* __restrict__ rob, float* __restrict__ out) {
    int lane = threadIdx.x & 63;
    int row  = blockIdx.x * 4 + (threadIdx.x >> 6);
    const float* qr = Q + (size_t)row * TT;
    float acc = 0.f;
    #pragma unroll
    for (int i = 0; i < 8; ++i) {
        int t = lane * 8 + i;
        acc = fmaf(silu_f(qr[t]), row_[t], acc);
    }
    #pragma unroll
    for (int off = 32; off > 0; off >>= 1) acc += __shfl_down(acc, off);
    if (lane == 0) out[row] = acc + rob[0];
}

} // namespace

extern "C" void kernel_launch(void* const* d_in, const int* in_sizes, int n_in,
                              void* d_out, int out_size, void* d_ws, size_t ws_size,
                              hipStream_t stream) {
    const float* x     = (const float*)d_in[0];
    const float* omega = (const float*)d_in[1];
    const float* G     = (const float*)d_in[2];
    const float* phase = (const float*)d_in[3];
    const float* l1_w  = (const float*)d_in[4];
    const float* l1_b  = (const float*)d_in[5];
    const float* mu_w  = (const float*)d_in[6];
    const float* mu_b  = (const float*)d_in[7];
    const float* sg_w  = (const float*)d_in[8];
    const float* sg_b  = (const float*)d_in[9];
    const float* alqg  = (const float*)d_in[10];
    const float* alqb  = (const float*)d_in[11];
    const float* alfg  = (const float*)d_in[12];
    const float* alfb  = (const float*)d_in[13];
    const float* a_w1  = (const float*)d_in[14];
    const float* a_b1  = (const float*)d_in[15];
    const float* a_w2  = (const float*)d_in[16];
    const float* a_b2  = (const float*)d_in[17];
    const float* mln_g = (const float*)d_in[18];
    const float* mln_b = (const float*)d_in[19];
    const float* m_w1  = (const float*)d_in[20];
    const float* m_b1  = (const float*)d_in[21];
    const float* m_w2  = (const float*)d_in[22];
    const float* m_b2  = (const float*)d_in[23];
    const float* ro_w  = (const float*)d_in[24];
    const float* ro_b  = (const float*)d_in[25];

    // ---- workspace layout (total 100,663,296 B == round-1 proven footprint) ----
    char* ws = (char*)d_ws;
    float*     Q    = (float*)ws;                          // 16 MB  [B,T] fp32
    _Float16*  h_hi = (_Float16*)(ws + 16777216);          //  8 MB  [B,T] f16
    _Float16*  h_lo = (_Float16*)(ws + 25165824);          //  8 MB  [B,T] f16
    _Float16*  mid  = (_Float16*)(ws + 33554432);          // 32 MB  [B,F] f16
    float*     MS   = (float*)(ws + 33554432);             // alias on mid: [B,1024] fp32
    _Float16*  wbuf = (_Float16*)(ws + 67108864);          // 32 MB  f16 weights

    _Float16* msw_hi = wbuf;                     // 4*1024*512 (mu/sig concat)
    _Float16* msw_lo = msw_hi + 2097152;
    _Float16* aw1    = msw_lo + 2097152;         // 4*2048*512
    _Float16* aw2    = aw1 + 4194304;
    _Float16* mw1    = aw2 + 4194304;            // 2*2048*512
    _Float16* mw2    = mw1 + 2097152;

    dim3 blk(256);
    const int BIG = 1 << 30;

    // merged weight conversion (re-done every call; inputs re-poisoned by harness)
    cvtall_kernel<<<14336, blk, 0, stream>>>(
        mu_w, sg_w, a_w1, a_w2, m_w1, m_w2,
        msw_hi, msw_lo, aw1, aw2, mw1, mw2);

    // fused tokenizer + layer-0 LN (hi+lo)
    tokln_kernel<<<BB, dim3(512), 0, stream>>>(
        x, l1_w, l1_b, alqg, alqb, Q, h_hi, h_lo);

    for (int i = 0; i < 4; ++i) {
        if (i > 0)
            ln_kernel<true><<<BB / 4, blk, 0, stream>>>(
                Q, alqg + i * TT, alqb + i * TT, h_hi, h_lo);
        // fused mu|sig SPLIT GEMM: N=1024, deep pipeline, tanh on mu half only
        gemmdp_kernel<256, 128, 32, 4, 2, 3, 2, true, 3, false, float>
            <<<dim3(BB / 256, 1024 / 128), dim3(512), 0, stream>>>(
            h_hi, h_lo, msw_hi + (size_t)i * 524288, msw_lo + (size_t)i * 524288,
            mu_b + i * TT, sg_b + i * TT, nullptr, MS, 1024, TT, TT);
        // fused attention update + LN -> h_hi
        attnln_kernel<<<BB, dim3(512), 0, stream>>>(
            Q, MS, x, omega, G, phase, alfg + i * TT, alfb + i * TT, h_hi);
        // w1: 8-phase 256x256 deep-pipelined kernel
        gemm8p_kernel<<<dim3(BB / 256, FF / 256), dim3(512), 0, stream>>>(
            h_hi, aw1 + (size_t)i * 1048576, a_b1 + i * FF, mid, FF, TT);
        // w2: NBUF=5 (80KB x 2 blocks/CU), D=4 lead
        gemmdp_kernel<128, 128, 32, 2, 4, 5, 4, false, 0, true, float>
            <<<dim3(BB / 128, TT / 128), dim3(512), 0, stream>>>(
            mid, nullptr, aw2 + (size_t)i * 1048576, nullptr,
            a_b2 + i * TT, a_b2 + i * TT, Q, Q, TT, FF, BIG);
    }
    for (int i = 0; i < 2; ++i) {
        ln_kernel<false><<<BB / 4, blk, 0, stream>>>(
            Q, mln_g + i * TT, mln_b + i * TT, h_hi, nullptr);
        gemm8p_kernel<<<dim3(BB / 256, FF / 256), dim3(512), 0, stream>>>(
            h_hi, mw1 + (size_t)i * 1048576, m_b1 + i * FF, mid, FF, TT);
        gemmdp_kernel<128, 128, 32, 2, 4, 5, 4, false, 0, true, float>
            <<<dim3(BB / 128, TT / 128), dim3(512), 0, stream>>>(
            mid, nullptr, mw2 + (size_t)i * 1048576, nullptr,
            m_b2 + i * TT, m_b2 + i * TT, Q, Q, TT, FF, BIG);
    }

    readout_kernel<<<BB / 4, blk, 0, stream>>>(Q, ro_w, ro_b, (float*)d_out);
}

// Round 12
// 715.854 us; speedup vs baseline: 1.1983x; 1.0110x over previous
//
#include <hip/hip_runtime.h>
#include <cmath>

namespace {

constexpr int BB = 8192;
constexpr int TT = 512;
constexpr int FF = 2048;
constexpr float EPS_LN  = 1e-5f;
constexpr float EPS_SIG = 1e-8f;

typedef _Float16 half8 __attribute__((ext_vector_type(8)));
typedef _Float16 half4 __attribute__((ext_vector_type(4)));
typedef float f32x4 __attribute__((ext_vector_type(4)));

typedef __attribute__((address_space(1))) void gvoid_t;
typedef __attribute__((address_space(3))) void lvoid_t;

__device__ __forceinline__ void async16(void* lds, const void* g) {
    __builtin_amdgcn_global_load_lds((gvoid_t*)g, (lvoid_t*)lds, 16, 0, 0);
}

__device__ __forceinline__ float silu_f(float v) {
    return v / (1.0f + expf(-v));
}
// fast silu: only for f16-rounded outputs (error ~1e-6 << f16 ulp)
__device__ __forceinline__ float silu_fast(float v) {
    return v * __builtin_amdgcn_rcpf(1.0f + __expf(-v));
}
// fast tanh: (e^{2v}-1)/(e^{2v}+1); clamp +-10 (exact: tanh saturates ~9.01 in f32)
__device__ __forceinline__ float tanh_fast(float v) {
    float t = __expf(2.0f * fminf(fmaxf(v, -10.0f), 10.0f));
    return (t - 1.0f) * __builtin_amdgcn_rcpf(t + 1.0f);
}

// ===== merged weight conversion: all 6 fp32->f16 conversions in ONE dispatch =====
__global__ __launch_bounds__(256) void cvtall_kernel(
    const float* __restrict__ mu_w, const float* __restrict__ sg_w,
    const float* __restrict__ a_w1, const float* __restrict__ a_w2,
    const float* __restrict__ m_w1, const float* __restrict__ m_w2,
    _Float16* __restrict__ msw_hi, _Float16* __restrict__ msw_lo,
    _Float16* __restrict__ aw1, _Float16* __restrict__ aw2,
    _Float16* __restrict__ mw1, _Float16* __restrict__ mw2) {
    int i = (blockIdx.x * 256 + threadIdx.x) * 4;     // < 14,680,064
    if (i < 2097152) {                                 // mu|sig cvtcat (hi+lo)
        const float* s; int base, ii = i;
        if (i < 1048576) { s = mu_w; base = 0; }
        else             { s = sg_w; base = 262144; ii -= 1048576; }
        int dst = ((ii >> 18) << 19) + base + (ii & 262143);
        float4 v = *(const float4*)(s + ii);
        half4 h, l;
        h[0] = (_Float16)v.x; h[1] = (_Float16)v.y;
        h[2] = (_Float16)v.z; h[3] = (_Float16)v.w;
        l[0] = (_Float16)(v.x - (float)h[0]);
        l[1] = (_Float16)(v.y - (float)h[1]);
        l[2] = (_Float16)(v.z - (float)h[2]);
        l[3] = (_Float16)(v.w - (float)h[3]);
        *(half4*)(msw_hi + dst) = h;
        *(half4*)(msw_lo + dst) = l;
        return;
    }
    const float* s; _Float16* d; int ii;
    if      (i <  6291456) { s = a_w1; d = aw1; ii = i -  2097152; }
    else if (i < 10485760) { s = a_w2; d = aw2; ii = i -  6291456; }
    else if (i < 12582912) { s = m_w1; d = mw1; ii = i - 10485760; }
    else                   { s = m_w2; d = mw2; ii = i - 12582912; }
    float4 v = *(const float4*)(s + ii);
    half4 h;
    h[0] = (_Float16)v.x; h[1] = (_Float16)v.y;
    h[2] = (_Float16)v.z; h[3] = (_Float16)v.w;
    *(half4*)(d + ii) = h;
}

// ==== fused tokenizer + first layernorm: Q = silu(x@l1), h = LN(Q)*g+b (hi+lo) ====
__global__ __launch_bounds__(512) void tokln_kernel(
    const float* __restrict__ x, const float* __restrict__ l1w,
    const float* __restrict__ l1b,
    const float* __restrict__ g, const float* __restrict__ bia,
    float* __restrict__ Q, _Float16* __restrict__ Y, _Float16* __restrict__ Ylo) {
    __shared__ float red[2][8];
    const int tid = threadIdx.x, b = blockIdx.x, t = tid;
    const float x0 = x[2 * b], x1 = x[2 * b + 1];
    float qn = silu_f(fmaf(x0, l1w[2 * t], fmaf(x1, l1w[2 * t + 1], l1b[t])));
    const size_t idx = (size_t)b * TT + t;
    Q[idx] = qn;
    const int wid = tid >> 6, lane = tid & 63;
    float s = qn;
    #pragma unroll
    for (int off = 32; off > 0; off >>= 1) s += __shfl_down(s, off);
    if (lane == 0) red[0][wid] = s;
    __syncthreads();
    float tot = 0.f;
    #pragma unroll
    for (int w = 0; w < 8; ++w) tot += red[0][w];
    float mean = tot * (1.0f / TT);
    float d = qn - mean;
    float ss = d * d;
    #pragma unroll
    for (int off = 32; off > 0; off >>= 1) ss += __shfl_down(ss, off);
    if (lane == 0) red[1][wid] = ss;
    __syncthreads();
    float vtot = 0.f;
    #pragma unroll
    for (int w = 0; w < 8; ++w) vtot += red[1][w];
    float rstd = rsqrtf(vtot * (1.0f / TT) + EPS_LN);
    float o = d * rstd * g[t] + bia[t];
    _Float16 hv = (_Float16)o;
    Y[idx] = hv;
    Ylo[idx] = (_Float16)(o - (float)hv);
}

// ------- layernorm (fp32 in, f16 out, optional f16 lo residual), wave per row -------
template <bool LO>
__global__ __launch_bounds__(256) void ln_kernel(
    const float* __restrict__ X, const float* __restrict__ g,
    const float* __restrict__ bia, _Float16* __restrict__ Y,
    _Float16* __restrict__ Ylo) {
    int lane = threadIdx.x & 63;
    int row  = blockIdx.x * 4 + (threadIdx.x >> 6);
    const float* xr = X + (size_t)row * TT;
    float v[8];
    {
        float4 a = *(const float4*)(xr + lane * 8);
        float4 c = *(const float4*)(xr + lane * 8 + 4);
        v[0]=a.x; v[1]=a.y; v[2]=a.z; v[3]=a.w;
        v[4]=c.x; v[5]=c.y; v[6]=c.z; v[7]=c.w;
    }
    float s = 0.f;
    #pragma unroll
    for (int i = 0; i < 8; ++i) s += v[i];
    #pragma unroll
    for (int off = 32; off > 0; off >>= 1) s += __shfl_down(s, off);
    float mean = __shfl(s, 0) * (1.0f / TT);
    float ss = 0.f;
    #pragma unroll
    for (int i = 0; i < 8; ++i) { float d = v[i] - mean; ss = fmaf(d, d, ss); }
    #pragma unroll
    for (int off = 32; off > 0; off >>= 1) ss += __shfl_down(ss, off);
    float var  = __shfl(ss, 0) * (1.0f / TT);
    float rstd = rsqrtf(var + EPS_LN);
    half8 hv, lv;
    #pragma unroll
    for (int i = 0; i < 8; ++i) {
        int t = lane * 8 + i;
        float o = (v[i] - mean) * rstd * g[t] + bia[t];
        hv[i] = (_Float16)o;
        if (LO) lv[i] = (_Float16)(o - (float)hv[i]);
    }
    *(half8*)(Y + (size_t)row * TT + lane * 8) = hv;
    if (LO) *(half8*)(Ylo + (size_t)row * TT + lane * 8) = lv;
}

// ====== 8-phase-style deep-pipelined 256x256 GEMM for w1 (T3+T4+T5, m201) ======
// 512 thr = 8 waves (2M x 4N), wave out 128x64 (MI=8, NI=4), BK=32, NK=16.
// LDS ring NBUF=4 x (A 256x32 + W 256x32) f16 = 128 KB.
// Per K-iter: head {vmcnt(8) counted; barrier}, then 4 PHASES:
// {ds_read a-pair (+4xb in phase 0) || stage 1 load of tile t+3 -> barrier ->
// setprio(1) 8 MFMA setprio(0) -> barrier}. vmcnt never drains mid-loop.
__global__ __launch_bounds__(512, 2) void gemm8p_kernel(
    const _Float16* __restrict__ A, const _Float16* __restrict__ W,
    const float* __restrict__ bias, _Float16* __restrict__ C, int N, int K) {
    constexpr int BM = 256, BN = 256, BK = 32, NBUF = 4;
    constexpr int ABUF = BM * BK;            // 8192 halves (== WBUF)
    constexpr int WOFF = NBUF * ABUF;

    __shared__ alignas(16) _Float16 lds[2 * NBUF * ABUF];   // 131072 B

    const int tid = threadIdx.x;
    const int m0  = blockIdx.x * BM;
    const int n0  = blockIdx.y * BN;

    const _Float16* gsrc[4];
    int off0[4];
    #pragma unroll
    for (int j = 0; j < 4; ++j) {
        int idx = j * 512 + tid;
        int isW = idx >> 10;
        int ch  = idx & 1023;
        int row = ch >> 2, sl = ch & 3;
        int src = sl ^ ((row >> 1) & 3);
        gsrc[j] = (isW ? W + (size_t)(n0 + row) * K
                       : A + (size_t)(m0 + row) * K) + src * 8;
        off0[j] = isW * WOFF + row * BK + sl * 8;
    }
    auto stage1 = [&](int buf, int k0, int j) {
        async16(&lds[off0[j] + buf * ABUF], gsrc[j] + k0);
    };

    const int wid  = tid >> 6;
    const int wr   = wid >> 2;               // 0..1
    const int wc   = wid & 3;                // 0..3
    const int lane = tid & 63;
    const int fr   = lane & 15;
    const int q    = lane >> 4;
    const int swz  = (q ^ ((fr >> 1) & 3)) * 8;

    const _Float16* aB = &lds[(wr * 128 + fr) * BK + swz];
    const _Float16* wB = &lds[WOFF + (wc * 64 + fr) * BK + swz];

    f32x4 acc[8][4];
    #pragma unroll
    for (int mi = 0; mi < 8; ++mi)
        #pragma unroll
        for (int ni = 0; ni < 4; ++ni) acc[mi][ni] = {0.f, 0.f, 0.f, 0.f};

    const int NK = K / BK;                   // 16

    #pragma unroll
    for (int s = 0; s < 3; ++s)
        #pragma unroll
        for (int j = 0; j < 4; ++j) stage1(s, s * BK, j);

    for (int t = 0; t < NK; ++t) {
        const int d = (t & 3) * ABUF;
        if (t < NK - 2)       { asm volatile("s_waitcnt vmcnt(8)" ::: "memory"); }
        else if (t == NK - 2) { asm volatile("s_waitcnt vmcnt(4)" ::: "memory"); }
        else                  { asm volatile("s_waitcnt vmcnt(0)" ::: "memory"); }
        __builtin_amdgcn_s_barrier();
        asm volatile("" ::: "memory");
        const bool st = (t < NK - 3);        // block-uniform
        half8 b0 = *(const half8*)(wB + d);
        half8 b1 = *(const half8*)(wB + d + 16 * BK);
        half8 b2 = *(const half8*)(wB + d + 32 * BK);
        half8 b3 = *(const half8*)(wB + d + 48 * BK);
        #pragma unroll
        for (int p = 0; p < 4; ++p) {
            half8 a0 = *(const half8*)(aB + d + (2 * p)     * 16 * BK);
            half8 a1 = *(const half8*)(aB + d + (2 * p + 1) * 16 * BK);
            if (st) stage1((t + 3) & 3, (t + 3) * BK, p);
            __builtin_amdgcn_s_barrier();
            asm volatile("" ::: "memory");
            __builtin_amdgcn_s_setprio(1);
            acc[2*p][0]   = __builtin_amdgcn_mfma_f32_16x16x32_f16(a0, b0, acc[2*p][0],   0, 0, 0);
            acc[2*p][1]   = __builtin_amdgcn_mfma_f32_16x16x32_f16(a0, b1, acc[2*p][1],   0, 0, 0);
            acc[2*p][2]   = __builtin_amdgcn_mfma_f32_16x16x32_f16(a0, b2, acc[2*p][2],   0, 0, 0);
            acc[2*p][3]   = __builtin_amdgcn_mfma_f32_16x16x32_f16(a0, b3, acc[2*p][3],   0, 0, 0);
            acc[2*p+1][0] = __builtin_amdgcn_mfma_f32_16x16x32_f16(a1, b0, acc[2*p+1][0], 0, 0, 0);
            acc[2*p+1][1] = __builtin_amdgcn_mfma_f32_16x16x32_f16(a1, b1, acc[2*p+1][1], 0, 0, 0);
            acc[2*p+1][2] = __builtin_amdgcn_mfma_f32_16x16x32_f16(a1, b2, acc[2*p+1][2], 0, 0, 0);
            acc[2*p+1][3] = __builtin_amdgcn_mfma_f32_16x16x32_f16(a1, b3, acc[2*p+1][3], 0, 0, 0);
            __builtin_amdgcn_s_setprio(0);
            __builtin_amdgcn_s_barrier();
            asm volatile("" ::: "memory");
        }
    }

    const int r0 = q * 4;
    #pragma unroll
    for (int mi = 0; mi < 8; ++mi) {
        #pragma unroll
        for (int ni = 0; ni < 4; ++ni) {
            const int col = n0 + wc * 64 + ni * 16 + fr;
            const float bv = bias[col];
            #pragma unroll
            for (int r = 0; r < 4; ++r) {
                const int row = m0 + wr * 128 + mi * 16 + r0 + r;
                C[(size_t)row * N + col] = (_Float16)silu_fast(acc[mi][ni][r] + bv);
            }
        }
    }
}

// ========== unified deep-pipelined MFMA GEMM (coarse ring; musig + w2) ==========
template <int BM, int BN, int BK, int WGM, int WGN, int NBUF, int MINW,
          bool SPLIT, int ACT, bool RESID, typename OutT>
__global__ __launch_bounds__(WGM * WGN * 64, MINW) void gemmdp_kernel(
    const _Float16* __restrict__ A, const _Float16* __restrict__ Alo,
    const _Float16* __restrict__ W, const _Float16* __restrict__ Wlo,
    const float* __restrict__ bias, const float* __restrict__ bias2,
    const float* __restrict__ R, OutT* __restrict__ C,
    int N, int K, int nsplit) {
    constexpr int THREADS = WGM * WGN * 64;
    constexpr int CPR  = BK / 8;                   // 16B chunks per row
    constexpr int NS   = SPLIT ? 2 : 1;
    constexpr int D    = NBUF - 1;
    constexpr int CH_A = NS * BM * CPR;
    constexpr int CH_T = NS * (BM + BN) * CPR;
    constexpr int LPT  = CH_T / THREADS;
    static_assert(CH_T % THREADS == 0 && CH_A % THREADS == 0, "staging split");
    constexpr int ABUF = NS * BM * BK;             // halves per buf (A region)
    constexpr int WBUF = NS * BN * BK;
    constexpr int WOFF = NBUF * ABUF;
    constexpr int WTM  = BM / WGM;
    constexpr int WTN  = BN / WGN;
    constexpr int MI   = WTM / 16;
    constexpr int NI   = WTN / 16;

    __shared__ alignas(16) _Float16 lds[NBUF * (ABUF + WBUF)];

    const int tid = threadIdx.x;
    const int m0  = blockIdx.x * BM;
    const int n0  = blockIdx.y * BN;

    const _Float16* Asrc[2] = {A, Alo};
    const _Float16* Wsrc[2] = {W, Wlo};

    const _Float16* gsrc[LPT];
    int off0[LPT], bstr[LPT];
    #pragma unroll
    for (int j = 0; j < LPT; ++j) {
        int idx = j * THREADS + tid;
        if (j * THREADS < CH_A) {
            int s   = idx / (BM * CPR);
            int rc  = idx % (BM * CPR);
            int row = rc / CPR, sl = rc % CPR;
            int src = sl ^ ((row >> 1) & (CPR - 1));
            gsrc[j] = Asrc[s] + (size_t)(m0 + row) * K + src * 8;
            off0[j] = (s * BM + row) * BK + sl * 8;
            bstr[j] = ABUF;
        } else {
            int i2  = idx - CH_A;
            int s   = i2 / (BN * CPR);
            int rc  = i2 % (BN * CPR);
            int row = rc / CPR, sl = rc % CPR;
            int src = sl ^ ((row >> 1) & (CPR - 1));
            gsrc[j] = Wsrc[s] + (size_t)(n0 + row) * K + src * 8;
            off0[j] = WOFF + (s * BN + row) * BK + sl * 8;
            bstr[j] = WBUF;
        }
    }

    auto stage = [&](int buf, int k0) {
        #pragma unroll
        for (int j = 0; j < LPT; ++j)
            async16(&lds[off0[j] + buf * bstr[j]], gsrc[j] + k0);
    };

    const int wid  = tid >> 6;
    const int wr   = wid / WGN;
    const int wc   = wid % WGN;
    const int lane = tid & 63;
    const int fr   = lane & 15;
    const int q    = lane >> 4;
    const int hxor = (fr >> 1) & (CPR - 1);

    const f32x4 vzero = {0.f, 0.f, 0.f, 0.f};
    f32x4 acc[MI][NI];
    #pragma unroll
    for (int mi = 0; mi < MI; ++mi)
        #pragma unroll
        for (int ni = 0; ni < NI; ++ni) acc[mi][ni] = vzero;

    auto body = [&](int buf) {
        const int da = buf * ABUF;
        const int dw = WOFF + buf * WBUF;
        #pragma unroll
        for (int ks = 0; ks < BK / 32; ++ks) {
            const int swz = ((ks * 4 + q) ^ hxor) * 8;
            half8 a[NS][MI], b[NS][NI];
            #pragma unroll
            for (int s = 0; s < NS; ++s) {
                #pragma unroll
                for (int mi = 0; mi < MI; ++mi)
                    a[s][mi] = *(const half8*)&lds[da + (s * BM + wr * WTM + mi * 16 + fr) * BK + swz];
                #pragma unroll
                for (int ni = 0; ni < NI; ++ni)
                    b[s][ni] = *(const half8*)&lds[dw + (s * BN + wc * WTN + ni * 16 + fr) * BK + swz];
            }
            __builtin_amdgcn_s_setprio(1);
            #pragma unroll
            for (int mi = 0; mi < MI; ++mi)
                #pragma unroll
                for (int ni = 0; ni < NI; ++ni)
                    acc[mi][ni] = __builtin_amdgcn_mfma_f32_16x16x32_f16(
                        a[0][mi], b[0][ni], acc[mi][ni], 0, 0, 0);
            if (SPLIT) {
                #pragma unroll
                for (int mi = 0; mi < MI; ++mi)
                    #pragma unroll
                    for (int ni = 0; ni < NI; ++ni)
                        acc[mi][ni] = __builtin_amdgcn_mfma_f32_16x16x32_f16(
                            a[1][mi], b[0][ni], acc[mi][ni], 0, 0, 0);
                #pragma unroll
                for (int mi = 0; mi < MI; ++mi)
                    #pragma unroll
                    for (int ni = 0; ni < NI; ++ni)
                        acc[mi][ni] = __builtin_amdgcn_mfma_f32_16x16x32_f16(
                            a[0][mi], b[1][ni], acc[mi][ni], 0, 0, 0);
            }
            __builtin_amdgcn_s_setprio(0);
        }
    };

    const int NK = K / BK;

    #pragma unroll
    for (int s = 0; s < D; ++s) stage(s, s * BK);

    int rbuf = 0, sbuf = D;
    for (int ki = 0; ki < NK - D; ++ki) {
        asm volatile("s_waitcnt vmcnt(%0)" :: "n"((D - 1) * LPT) : "memory");
        __builtin_amdgcn_s_barrier();
        asm volatile("" ::: "memory");
        stage(sbuf, (ki + D) * BK);
        sbuf = (sbuf + 1 == NBUF) ? 0 : sbuf + 1;
        body(rbuf);
        rbuf = (rbuf + 1 == NBUF) ? 0 : rbuf + 1;
    }
    if constexpr (D >= 4) {
        asm volatile("s_waitcnt vmcnt(%0)" :: "n"(3 * LPT) : "memory");
        __builtin_amdgcn_s_barrier();
        asm volatile("" ::: "memory");
        body(rbuf);
        rbuf = (rbuf + 1 == NBUF) ? 0 : rbuf + 1;
    }
    if constexpr (D >= 3) {
        asm volatile("s_waitcnt vmcnt(%0)" :: "n"(2 * LPT) : "memory");
        __builtin_amdgcn_s_barrier();
        asm volatile("" ::: "memory");
        body(rbuf);
        rbuf = (rbuf + 1 == NBUF) ? 0 : rbuf + 1;
    }
    if constexpr (D >= 2) {
        asm volatile("s_waitcnt vmcnt(%0)" :: "n"(1 * LPT) : "memory");
        __builtin_amdgcn_s_barrier();
        asm volatile("" ::: "memory");
        body(rbuf);
        rbuf = (rbuf + 1 == NBUF) ? 0 : rbuf + 1;
    }
    asm volatile("s_waitcnt vmcnt(0)" ::: "memory");
    __builtin_amdgcn_s_barrier();
    asm volatile("" ::: "memory");
    body(rbuf);

    const bool fh = (n0 < nsplit);
    const float* bp = fh ? bias : bias2;
    const int coff = fh ? 0 : nsplit;
    const int r0 = q * 4;
    #pragma unroll
    for (int mi = 0; mi < MI; ++mi) {
        #pragma unroll
        for (int ni = 0; ni < NI; ++ni) {
            const int col = n0 + wc * WTN + ni * 16 + fr;
            const float bv = bp[col - coff];
            #pragma unroll
            for (int r = 0; r < 4; ++r) {
                const int row = m0 + wr * WTM + mi * 16 + r0 + r;
                float v = acc[mi][ni][r] + bv;
                if (ACT == 1) v = silu_fast(v);
                if (ACT == 3 && fh) v = tanh_fast(v);
                if (RESID) v += R[(size_t)row * N + col];
                C[(size_t)row * N + col] = (OutT)v;
            }
        }
    }
}

// ==== fused attention update + layernorm: Q += sum_k S*H; h = LN(Q)*g+b -> f16 ====
// R12: NO LDS staging. Thread tid consumes exactly its OWN contiguous 8 elements
// e = tid*8+k, so the old cs/gs LDS round-trip was a no-op transpose of
// L2-resident tables (omega/G/phase = 256KB total, cached chip-wide). Direct
// per-thread loads: omega 4x float4 (64B), G/phase 2x float4 each (32B).
// Removes 32 LDS ops + 1 barrier per thread and the 33KB LDS arrays
// (occupancy cap 4 blocks/CU by LDS -> thread-slot cap only).
__global__ __launch_bounds__(512) void attnln_kernel(
    float* __restrict__ Q, const float* __restrict__ MS,
    const float* __restrict__ x,
    const float* __restrict__ omega, const float* __restrict__ G,
    const float* __restrict__ phase,
    const float* __restrict__ g, const float* __restrict__ bia,
    _Float16* __restrict__ Y) {
    __shared__ float red[2][8];
    const int tid = threadIdx.x;
    const int b   = blockIdx.x;
    const int t   = tid;
    const float x0 = x[2 * b], x1 = x[2 * b + 1];
    // own 8 (t,k) elements, contiguous: omega[16t..16t+16), G/phase[8t..8t+8)
    float4 om[4], gv[2], ph[2];
    #pragma unroll
    for (int i = 0; i < 4; ++i) om[i] = *(const float4*)(omega + t * 16 + i * 4);
    #pragma unroll
    for (int i = 0; i < 2; ++i) gv[i] = *(const float4*)(G + t * 8 + i * 4);
    #pragma unroll
    for (int i = 0; i < 2; ++i) ph[i] = *(const float4*)(phase + t * 8 + i * 4);
    const float* omf = (const float*)om;
    const float* gvf = (const float*)gv;
    const float* phf = (const float*)ph;
    float mu  = MS[(size_t)b * 1024 + t];
    float sig = MS[(size_t)b * 1024 + 512 + t];
    float inv = -0.5f * __builtin_amdgcn_rcpf(fmaf(sig, sig, EPS_SIG));
    float acc = 0.f;
    #pragma unroll
    for (int k = 0; k < 8; ++k) {
        float arg = fmaf(omf[2 * k], x0, fmaf(omf[2 * k + 1], x1, phf[k]));
        float d = gvf[k] - mu;
        acc = fmaf(__expf(d * d * inv), __cosf(arg), acc);
    }
    const size_t idx = (size_t)b * TT + t;
    float qn = Q[idx] + acc;
    Q[idx] = qn;
    const int wid = tid >> 6, lane = tid & 63;
    float s = qn;
    #pragma unroll
    for (int off = 32; off > 0; off >>= 1) s += __shfl_down(s, off);
    if (lane == 0) red[0][wid] = s;
    __syncthreads();
    float tot = 0.f;
    #pragma unroll
    for (int w = 0; w < 8; ++w) tot += red[0][w];
    float mean = tot * (1.0f / TT);
    float d = qn - mean;
    float ss = d * d;
    #pragma unroll
    for (int off = 32; off > 0; off >>= 1) ss += __shfl_down(ss, off);
    if (lane == 0) red[1][wid] = ss;
    __syncthreads();
    float vtot = 0.f;
    #pragma unroll
    for (int w = 0; w < 8; ++w) vtot += red[1][w];
    float rstd = rsqrtf(vtot * (1.0f / TT) + EPS_LN);
    Y[idx] = (_Float16)(d * rstd * g[t] + bia[t]);
}

// ---------------- readout: out[b] = silu(Q[b,:]) . ro_w + ro_b ----------------
__global__ __launch_bounds__(256) void readout_kernel(
    const float* __restrict__ Q, const float* __restrict__ row_,
    const float* __restrict__ rob, float* __restrict__ out) {
    int lane = threadIdx.x & 63;
    int row  = blockIdx.x * 4 + (threadIdx.x >> 6);
    const float* qr = Q + (size_t)row * TT;
    float acc = 0.f;
    #pragma unroll
    for (int i = 0; i < 8; ++i) {
        int t = lane * 8 + i;
        acc = fmaf(silu_f(qr[t]), row_[t], acc);
    }
    #pragma unroll
    for (int off = 32; off > 0; off >>= 1) acc += __shfl_down(acc, off);
    if (lane == 0) out[row] = acc + rob[0];
}

} // namespace

extern "C" void kernel_launch(void* const* d_in, const int* in_sizes, int n_in,
                              void* d_out, int out_size, void* d_ws, size_t ws_size,
                              hipStream_t stream) {
    const float* x     = (const float*)d_in[0];
    const float* omega = (const float*)d_in[1];
    const float* G     = (const float*)d_in[2];
    const float* phase = (const float*)d_in[3];
    const float* l1_w  = (const float*)d_in[4];
    const float* l1_b  = (const float*)d_in[5];
    const float* mu_w  = (const float*)d_in[6];
    const float* mu_b  = (const float*)d_in[7];
    const float* sg_w  = (const float*)d_in[8];
    const float* sg_b  = (const float*)d_in[9];
    const float* alqg  = (const float*)d_in[10];
    const float* alqb  = (const float*)d_in[11];
    const float* alfg  = (const float*)d_in[12];
    const float* alfb  = (const float*)d_in[13];
    const float* a_w1  = (const float*)d_in[14];
    const float* a_b1  = (const float*)d_in[15];
    const float* a_w2  = (const float*)d_in[16];
    const float* a_b2  = (const float*)d_in[17];
    const float* mln_g = (const float*)d_in[18];
    const float* mln_b = (const float*)d_in[19];
    const float* m_w1  = (const float*)d_in[20];
    const float* m_b1  = (const float*)d_in[21];
    const float* m_w2  = (const float*)d_in[22];
    const float* m_b2  = (const float*)d_in[23];
    const float* ro_w  = (const float*)d_in[24];
    const float* ro_b  = (const float*)d_in[25];

    // ---- workspace layout (total 100,663,296 B == round-1 proven footprint) ----
    char* ws = (char*)d_ws;
    float*     Q    = (float*)ws;                          // 16 MB  [B,T] fp32
    _Float16*  h_hi = (_Float16*)(ws + 16777216);          //  8 MB  [B,T] f16
    _Float16*  h_lo = (_Float16*)(ws + 25165824);          //  8 MB  [B,T] f16
    _Float16*  mid  = (_Float16*)(ws + 33554432);          // 32 MB  [B,F] f16
    float*     MS   = (float*)(ws + 33554432);             // alias on mid: [B,1024] fp32
    _Float16*  wbuf = (_Float16*)(ws + 67108864);          // 32 MB  f16 weights

    _Float16* msw_hi = wbuf;                     // 4*1024*512 (mu/sig concat)
    _Float16* msw_lo = msw_hi + 2097152;
    _Float16* aw1    = msw_lo + 2097152;         // 4*2048*512
    _Float16* aw2    = aw1 + 4194304;
    _Float16* mw1    = aw2 + 4194304;            // 2*2048*512
    _Float16* mw2    = mw1 + 2097152;

    dim3 blk(256);
    const int BIG = 1 << 30;

    // merged weight conversion (re-done every call; inputs re-poisoned by harness)
    cvtall_kernel<<<14336, blk, 0, stream>>>(
        mu_w, sg_w, a_w1, a_w2, m_w1, m_w2,
        msw_hi, msw_lo, aw1, aw2, mw1, mw2);

    // fused tokenizer + layer-0 LN (hi+lo)
    tokln_kernel<<<BB, dim3(512), 0, stream>>>(
        x, l1_w, l1_b, alqg, alqb, Q, h_hi, h_lo);

    for (int i = 0; i < 4; ++i) {
        if (i > 0)
            ln_kernel<true><<<BB / 4, blk, 0, stream>>>(
                Q, alqg + i * TT, alqb + i * TT, h_hi, h_lo);
        // fused mu|sig SPLIT GEMM: N=1024, deep pipeline, tanh on mu half only
        gemmdp_kernel<256, 128, 32, 4, 2, 3, 2, true, 3, false, float>
            <<<dim3(BB / 256, 1024 / 128), dim3(512), 0, stream>>>(
            h_hi, h_lo, msw_hi + (size_t)i * 524288, msw_lo + (size_t)i * 524288,
            mu_b + i * TT, sg_b + i * TT, nullptr, MS, 1024, TT, TT);
        // fused attention update + LN -> h_hi (LDS-free)
        attnln_kernel<<<BB, dim3(512), 0, stream>>>(
            Q, MS, x, omega, G, phase, alfg + i * TT, alfb + i * TT, h_hi);
        // w1: 8-phase 256x256 deep-pipelined kernel
        gemm8p_kernel<<<dim3(BB / 256, FF / 256), dim3(512), 0, stream>>>(
            h_hi, aw1 + (size_t)i * 1048576, a_b1 + i * FF, mid, FF, TT);
        // w2: NBUF=5 (80KB x 2 blocks/CU), D=4 lead
        gemmdp_kernel<128, 128, 32, 2, 4, 5, 4, false, 0, true, float>
            <<<dim3(BB / 128, TT / 128), dim3(512), 0, stream>>>(
            mid, nullptr, aw2 + (size_t)i * 1048576, nullptr,
            a_b2 + i * TT, a_b2 + i * TT, Q, Q, TT, FF, BIG);
    }
    for (int i = 0; i < 2; ++i) {
        ln_kernel<false><<<BB / 4, blk, 0, stream>>>(
            Q, mln_g + i * TT, mln_b + i * TT, h_hi, nullptr);
        gemm8p_kernel<<<dim3(BB / 256, FF / 256), dim3(512), 0, stream>>>(
            h_hi, mw1 + (size_t)i * 1048576, m_b1 + i * FF, mid, FF, TT);
        gemmdp_kernel<128, 128, 32, 2, 4, 5, 4, false, 0, true, float>
            <<<dim3(BB / 128, TT / 128), dim3(512), 0, stream>>>(
            mid, nullptr, mw2 + (size_t)i * 1048576, nullptr,
            m_b2 + i * TT, m_b2 + i * TT, Q, Q, TT, FF, BIG);
    }

    readout_kernel<<<BB / 4, blk, 0, stream>>>(Q, ro_w, ro_b, (float*)d_out);
}